// Round 19
// baseline (172.371 us; speedup 1.0000x reference)
//
#include <hip/hip_runtime.h>
#include <cmath>

#define HW   16384
#define Wd   128
#define Hd   128
#define NB   4

typedef __attribute__((ext_vector_type(8))) _Float16 h16x8;
typedef __attribute__((ext_vector_type(4))) float f32x4;
typedef __attribute__((ext_vector_type(4))) unsigned int u32x4;

__device__ inline unsigned short f2h(float f) {
    _Float16 h = (_Float16)f;
    return __builtin_bit_cast(unsigned short, h);
}
__device__ inline _Float16 u2h(unsigned short u) {
    return __builtin_bit_cast(_Float16, u);
}

// ---------- fused prep: weight repacks (fp16 MFMA A-frag layout) + bias + NHWC transposes ----------
__device__ inline void repack_one(int idx, const float* __restrict__ s1, const float* __restrict__ s2,
                                  int Osplit, int O, int CIN, int KS, unsigned short* __restrict__ dst) {
    int e    = idx & 7;
    int lane = (idx >> 3) & 63;
    int ks   = (idx >> 9) % KS;
    int m    = (idx / (512 * KS)) & 3;
    int k    = idx / (2048 * KS);
    int oc = m * 16 + (lane & 15);
    int c  = ks * 32 + (lane >> 4) * 8 + e;
    float v = 0.f;
    if (oc < O && c < CIN)
        v = (oc < Osplit) ? s1[((size_t)oc * CIN + c) * 9 + k]
                          : s2[((size_t)(oc - Osplit) * CIN + c) * 9 + k];
    dst[idx] = f2h(v);
}

__global__ __launch_bounds__(256) void prep(
    const float* __restrict__ input, const float* __restrict__ offset,
    const float* __restrict__ w_off1, const float* __restrict__ w_off2,
    const float* __restrict__ b_off1, const float* __restrict__ b_off2,
    const float* __restrict__ w1, const float* __restrict__ w2, const float* __restrict__ w_last,
    unsigned short* __restrict__ xn, unsigned short* __restrict__ offn,
    unsigned short* __restrict__ wfo, unsigned short* __restrict__ wf1,
    unsigned short* __restrict__ wf2, unsigned short* __restrict__ wfl,
    float* __restrict__ bias54)
{
    int blk = blockIdx.x;
    if (blk < 512) {
        int t = blk * 256 + threadIdx.x;
        if (t < 65536) {
            int b = t >> 14, p = t & 16383;
            const float* s = input + ((size_t)b * 64) * HW + p;
            unsigned short* d = xn + (size_t)t * 64;
#pragma unroll
            for (int g = 0; g < 8; g++) {
                unsigned short pk[8];
#pragma unroll
                for (int e = 0; e < 8; e++) pk[e] = f2h(s[(size_t)(g * 8 + e) * HW]);
                *(u32x4*)(d + g * 8) = *(u32x4*)pk;
            }
        } else {
            int u = t - 65536;
            int b = u >> 14, p = u & 16383;
            const float* s = offset + ((size_t)b * 32) * HW + p;
            unsigned short* d = offn + (size_t)u * 32;
#pragma unroll
            for (int g = 0; g < 4; g++) {
                unsigned short pk[8];
#pragma unroll
                for (int e = 0; e < 8; e++) pk[e] = f2h(s[(size_t)(g * 8 + e) * HW]);
                *(u32x4*)(d + g * 8) = *(u32x4*)pk;
            }
        }
    } else {
        int u = (blk - 512) * 256 + threadIdx.x;
        if (u < 18432)        repack_one(u, w_off1, w_off1, 27, 27, 32, 1, wfo);
        else if (u < 36864)   repack_one(u - 18432, w_off2, w_off2, 27, 27, 32, 1, wfo + 18432);
        else if (u < 73728)   repack_one(u - 36864, w1, w1, 64, 64, 64, 2, wf1);
        else if (u < 110592)  repack_one(u - 73728, w2, w2, 64, 64, 64, 2, wf2);
        else if (u < 147456)  repack_one(u - 110592, w_last, w_last, 64, 64, 64, 2, wfl);
        else if (u < 147510) {
            int j = u - 147456;
            bias54[j] = (j < 27) ? b_off1[j] : b_off2[j - 27];
        }
    }
}

// ---------- conv3x3 CIN=64 (final conv), LDS-staged window, 8 waves kh-split ----------
__global__ __launch_bounds__(512, 8) void conv_stage64(
    const unsigned short* __restrict__ xn, const unsigned short* __restrict__ wf,
    const float* __restrict__ bias, float* __restrict__ out)
{
    __shared__ __align__(16) unsigned short stage[198 * 64];   // 3x66 px x 64ch
    int lb = ((blockIdx.x & 7) << 7) | (blockIdx.x >> 3);
    int t = threadIdx.x;
    int pxbase = lb * 64;
    int b = pxbase >> 14;
    int pbase = pxbase & 16383;
    int rowbase = pbase >> 7, colbase = pbase & 127;
    const unsigned short* xb = xn + ((size_t)(b << 14)) * 64;

    for (int q = t; q < 1584; q += 512) {
        int ps = q >> 3, j = q & 7;
        int ly = ps / 66, lx = ps - ly * 66;
        int y = rowbase - 1 + ly, x = colbase - 1 + lx;
        bool ok = (y >= 0) & (y < Hd) & (x >= 0) & (x < Wd);
        u32x4 v = {0, 0, 0, 0};
        if (ok) v = *(const u32x4*)(xb + ((size_t)(y * Wd + x)) * 64 + j * 8);
        *(u32x4*)(stage + ps * 64 + ((j ^ (ps & 7)) << 3)) = v;
    }
    __syncthreads();

    int lane = t & 63;
    int wave = t >> 6;
    int kh = wave >> 2;
    int wv = wave & 3;
    int sp = wv * 16 + (lane & 15);
    int px = pxbase + sp;
    int p = px & 16383;
    int cg = lane >> 4;
    int cch = kh * 4 + cg;

    const h16x8* wfv = (const h16x8*)wf;
    f32x4 acc[4];
#pragma unroll
    for (int m = 0; m < 4; m++) acc[m] = (f32x4){0.f, 0.f, 0.f, 0.f};

#pragma unroll
    for (int k = 0; k < 9; k++) {
        int ps = (k / 3) * 66 + sp + (k % 3);
        h16x8 bq = *(const h16x8*)(stage + ps * 64 + ((cch ^ (ps & 7)) << 3));
        h16x8 aF[4];
#pragma unroll
        for (int m = 0; m < 4; m++)
            aF[m] = wfv[((k * 4 + m) * 2 + kh) * 64 + lane];
#pragma unroll
        for (int m = 0; m < 4; m++)
            acc[m] = __builtin_amdgcn_mfma_f32_16x16x32_f16(aF[m], bq, acc[m], 0, 0, 0);
    }

    __syncthreads();                 // stage reads done; red aliases stage
    float* red = (float*)stage;
    if (kh == 1) {
#pragma unroll
        for (int m = 0; m < 4; m++)
#pragma unroll
            for (int j = 0; j < 4; j++)
                red[(m * 4 + j) * 256 + wv * 64 + lane] = acc[m][j];
    }
    __syncthreads();
    if (kh == 0) {
#pragma unroll
        for (int m = 0; m < 4; m++) {
            int ocb = m * 16 + cg * 4;
#pragma unroll
            for (int r = 0; r < 4; r++) {
                int oc = ocb + r;
                float v = acc[m][r] + red[(m * 4 + r) * 256 + wv * 64 + lane] + bias[oc];
                out[((size_t)b * 64 + oc) * HW + p] = v;
            }
        }
    }
}

// ---------- DCNv2 sampling helpers ----------
struct Tap { float w00, w01, w10, w11; int o00, o01, o10, o11; };

__device__ inline Tap mkparams(float oy, float ox, float mv, int row, int col, int k) {
    Tap P;
    float mk = 1.f / (1.f + __expf(-mv));
    float ys = (float)(row + k / 3 - 1) + oy;
    float xs = (float)(col + k % 3 - 1) + ox;
    float y0f = floorf(ys), x0f = floorf(xs);
    float fy = ys - y0f, fx = xs - x0f;
    int y0 = (int)y0f, x0 = (int)x0f;
    int y1 = y0 + 1, x1 = x0 + 1;
    bool vy0 = (y0 >= 0) & (y0 < Hd);
    bool vy1 = (y1 >= 0) & (y1 < Hd);
    bool vx0 = (x0 >= 0) & (x0 < Wd);
    bool vx1 = (x1 >= 0) & (x1 < Wd);
    P.w00 = (vy0 && vx0) ? (1.f - fy) * (1.f - fx) * mk : 0.f;
    P.w01 = (vy0 && vx1) ? (1.f - fy) * fx * mk : 0.f;
    P.w10 = (vy1 && vx0) ? fy * (1.f - fx) * mk : 0.f;
    P.w11 = (vy1 && vx1) ? fy * fx * mk : 0.f;
    int iy0 = min(max(y0, 0), Hd - 1) * Wd;
    int iy1 = min(max(y1, 0), Hd - 1) * Wd;
    int ix0 = min(max(x0, 0), Wd - 1);
    int ix1 = min(max(x1, 0), Wd - 1);
    P.o00 = iy0 + ix0; P.o01 = iy0 + ix1; P.o10 = iy1 + ix0; P.o11 = iy1 + ix1;
    return P;
}

// ---------- DCNv2, sliding-window: one block = 2 consecutive row-segments ----------
// Main window: 7 row-slabs (PERSISTENT, dedicated LDS), slab(y) = y % 7; seg 1 stages 1 new row.
// offn window: re-staged FULLY each segment (scratch is clobbered by tbl/red between segments
//              — R18's NaN bug was offstage persistence across that clobber).
// scratch time-share (within one segment only):
//   A: offstage(0..12672) -> B: read offstage, write omt(12672..16128)
//   -> C: read omt, write tbl(0..9216) -> E: read tbl -> F: red(0..16384) -> G: read red.
// EPI 0: leaky -> outn. EPI 1: + residn (NHWC fp16) -> outn.
template<int EPI>
__global__ __launch_bounds__(512, 4) void dcn_slide(
    const unsigned short* __restrict__ xn, const unsigned short* __restrict__ offn,
    const unsigned short* __restrict__ wfo, const float* __restrict__ obias,
    const unsigned short* __restrict__ wf, const float* __restrict__ bias,
    const unsigned short* __restrict__ residn, unsigned short* __restrict__ outn)
{
    __shared__ __align__(16) unsigned short stage[490 * 64];   // 62.7KB persistent slab window
    __shared__ __align__(16) char scratch[16512];
    unsigned short* offstage = (unsigned short*)scratch;       // 12672B  [A..B]
    unsigned short* omt      = (unsigned short*)(scratch + 12672); // 3456B fp16 [B..C]
    unsigned*       tbl      = (unsigned*)scratch;             // 9216B   [C..E] (alias offstage)
    float*          red      = (float*)scratch;                // 16384B  [F]    (alias all)

    int Bw = ((blockIdx.x & 7) << 6) | (blockIdx.x >> 3);      // 512 blocks, XCD swizzle
    int t = threadIdx.x;
    int lane = t & 63;
    int wave = t >> 6;
    int kh = wave >> 2;
    int wv = wave & 3;
    int cg = lane >> 4;
    int c0 = kh * 32 + cg * 8;
    int cch = kh * 4 + cg;
    int sp = wv * 16 + (lane & 15);

    int b  = Bw >> 7;            // batch
    int rp = (Bw >> 1) & 63;     // row pair
    int ch = Bw & 1;             // col half
    int r0 = rp * 2;
    int colbase = ch * 64;
    int xbase = colbase - 3;

    const unsigned short* xb = xn + ((size_t)(b << 14)) * 64;
    const unsigned short* ob = offn + ((size_t)(b << 14)) * 32;
    const h16x8* wfv = (const h16x8*)wf;
    const h16x8* wfvo = (const h16x8*)wfo;

    for (int si = 0; si < 2; ++si) {
        int rowbase = r0 + si;
        int ybase = rowbase - 3;
        int pbase = (rowbase << 7) + colbase;

        // ---- phase A: staging ----
        // offn 3-row window: re-stage fully EVERY segment (scratch was clobbered by tbl/red)
        for (int q = t; q < 792; q += 512) {
            int psl = q >> 2, j = q & 3;
            int ly = psl / 66, lx = psl - ly * 66;
            int wy = rowbase - 1 + ly;
            int x = colbase - 1 + lx;
            int slab = (wy + 129) % 3;
            int ps = slab * 66 + lx;
            bool ok = (wy >= 0) & (wy < Hd) & (x >= 0) & (x < Wd);
            u32x4 v = {0, 0, 0, 0};
            if (ok) v = *(const u32x4*)(ob + ((size_t)(wy * Wd + x)) * 32 + j * 8);
            *(u32x4*)(offstage + ps * 32 + ((j ^ (ps & 3)) << 3)) = v;
        }
        if (si == 0) {
            for (int q = t; q < 3920; q += 512) {          // main: 7 rows
                int psl = q >> 3, j = q & 7;
                int ly = psl / 70, lx = psl - ly * 70;
                int y = min(max(ybase + ly, 0), Hd - 1);
                int x = min(max(xbase + lx, 0), Wd - 1);
                int ps = (y % 7) * 70 + lx;
                u32x4 v = *(const u32x4*)(xb + ((size_t)(y * Wd + x)) * 64 + j * 8);
                *(u32x4*)(stage + ps * 64 + ((j ^ (ps & 7)) << 3)) = v;
            }
        } else {
            for (int q = t; q < 560; q += 512) {           // main: +1 new row only
                int lx = q >> 3, j = q & 7;
                int y = min(rowbase + 3, Hd - 1);
                int x = min(max(xbase + lx, 0), Wd - 1);
                int ps = (y % 7) * 70 + lx;
                u32x4 v = *(const u32x4*)(xb + ((size_t)(y * Wd + x)) * 64 + j * 8);
                *(u32x4*)(stage + ps * 64 + ((j ^ (ps & 7)) << 3)) = v;
            }
        }
        __syncthreads();

        // ---- phase B: offset conv, waves 0-3 (27 oc, m-tiles 0..1) -> omt fp16 ----
        if (wave < 4) {
            int osp = wave * 16 + (lane & 15);
            int cg4 = lane >> 4;
            f32x4 oacc[2];
#pragma unroll
            for (int m = 0; m < 2; m++) oacc[m] = (f32x4){0.f, 0.f, 0.f, 0.f};
#pragma unroll
            for (int k = 0; k < 9; k++) {
                int wy = rowbase - 1 + k / 3;
                int slab = (wy + 129) % 3;
                int ps = slab * 66 + osp + (k % 3);
                h16x8 bq = *(const h16x8*)(offstage + ps * 32 + ((cg4 ^ (ps & 3)) << 3));
#pragma unroll
                for (int m = 0; m < 2; m++) {
                    h16x8 aF = wfvo[(k * 4 + m) * 64 + lane];
                    oacc[m] = __builtin_amdgcn_mfma_f32_16x16x32_f16(aF, bq, oacc[m], 0, 0, 0);
                }
            }
#pragma unroll
            for (int m = 0; m < 2; m++) {
                int ocb = m * 16 + cg4 * 4;
#pragma unroll
                for (int r = 0; r < 4; r++) {
                    int oc = ocb + r;
                    if (oc < 27) omt[oc * 64 + osp] = f2h(oacc[m][r] + obias[oc]);
                }
            }
        }
        __syncthreads();

        // ---- phase C: taps -> packed b128 records ----
        for (int s = t; s < 576; s += 512) {
            int k = s >> 6, sp2 = s & 63;
            int row = rowbase, col = colbase + sp2;
            float oy = (float)u2h(omt[(2 * k) * 64 + sp2]);
            float ox = (float)u2h(omt[(2 * k + 1) * 64 + sp2]);
            float mv = (float)u2h(omt[(18 + k) * 64 + sp2]);
            Tap P = mkparams(oy, ox, mv, row, col, k);

            unsigned a[4];
            int oo[4] = {P.o00, P.o01, P.o10, P.o11};
#pragma unroll
            for (int c = 0; c < 4; c++) {
                int o = oo[c];
                int y = o >> 7, x = o & 127;
                int ly = y - ybase, lx = x - xbase;
                bool inw = ((unsigned)ly < 7u) & ((unsigned)lx < 70u);
                int ps = (y % 7) * 70 + min(max(lx, 0), 69);
                a[c] = inw ? (unsigned)((ps << 3) | (ps & 7)) : (0x8000u | (unsigned)o);
            }
            u32x4 pk4 = { a[0] | (a[1] << 16),
                          a[2] | (a[3] << 16),
                          (unsigned)f2h(P.w00) | ((unsigned)f2h(P.w01) << 16),
                          (unsigned)f2h(P.w10) | ((unsigned)f2h(P.w11) << 16) };
            *(u32x4*)&tbl[s * 4] = pk4;
        }
        __syncthreads();

        // ---- phase E: main loop ----
        f32x4 acc[4];
#pragma unroll
        for (int m = 0; m < 4; m++) acc[m] = (f32x4){0.f, 0.f, 0.f, 0.f};

#pragma unroll
        for (int k = 0; k < 9; k++) {
            int s = k * 64 + sp;
            u32x4 tv = *(const u32x4*)&tbl[s * 4];
            unsigned a01 = tv[0], a23 = tv[1], w01 = tv[2], w23 = tv[3];

            unsigned code[4] = { a01 & 0xffffu, a01 >> 16, a23 & 0xffffu, a23 >> 16 };
            h16x8 gc[4];
#pragma unroll
            for (int c = 0; c < 4; c++)
                gc[c] = *(const h16x8*)((const char*)stage + (((code[c] & 0xFFFu) ^ (unsigned)cch) << 4));

            if (__builtin_expect((a01 | a23) & 0x80008000u, 0)) {
#pragma unroll
                for (int c = 0; c < 4; c++)
                    if (code[c] & 0x8000u)
                        gc[c] = *(const h16x8*)(xb + (size_t)(code[c] & 0x7fffu) * 64 + c0);
            }

            _Float16 h00 = u2h((unsigned short)(w01 & 0xffffu));
            _Float16 h01 = u2h((unsigned short)(w01 >> 16));
            _Float16 h10 = u2h((unsigned short)(w23 & 0xffffu));
            _Float16 h11 = u2h((unsigned short)(w23 >> 16));
            h16x8 bF = gc[0] * h00;
            bF = gc[1] * h01 + bF;
            bF = gc[2] * h10 + bF;
            bF = gc[3] * h11 + bF;

            h16x8 aF[4];
#pragma unroll
            for (int m = 0; m < 4; m++)
                aF[m] = wfv[((k * 4 + m) * 2 + kh) * 64 + lane];
#pragma unroll
            for (int m = 0; m < 4; m++)
                acc[m] = __builtin_amdgcn_mfma_f32_16x16x32_f16(aF[m], bF, acc[m], 0, 0, 0);
        }
        __syncthreads();

        // ---- phase F: kh reduce (red aliases scratch, NOT stage) ----
        if (kh == 1) {
#pragma unroll
            for (int m = 0; m < 4; m++)
#pragma unroll
                for (int j = 0; j < 4; j++)
                    red[(m * 4 + j) * 256 + wv * 64 + lane] = acc[m][j];
        }
        __syncthreads();

        // ---- phase G: epilogue ----
        if (kh == 0) {
            int px = (b << 14) + pbase + sp;
            unsigned short* drow = outn + (size_t)px * 64;
            const unsigned short* rrow = (EPI == 1) ? residn + (size_t)px * 64 : nullptr;
#pragma unroll
            for (int m = 0; m < 4; m++) {
                int ocb = m * 16 + cg * 4;
                float rv[4] = {0.f, 0.f, 0.f, 0.f};
                if (EPI == 1) {
                    ushort4 rr = *(const ushort4*)(rrow + ocb);
                    rv[0] = (float)u2h(rr.x); rv[1] = (float)u2h(rr.y);
                    rv[2] = (float)u2h(rr.z); rv[3] = (float)u2h(rr.w);
                }
                unsigned short pk[4];
#pragma unroll
                for (int r = 0; r < 4; r++) {
                    int oc = ocb + r;
                    float v = acc[m][r] + red[(m * 4 + r) * 256 + wv * 64 + lane] + bias[oc];
                    if (EPI == 0) v = (v >= 0.f) ? v : 0.01f * v;
                    if (EPI == 1) v += rv[r];
                    pk[r] = f2h(v);
                }
                *(ushort4*)(drow + ocb) = *(ushort4*)pk;
            }
        }
        __syncthreads();   // protect red before next segment's phase A rewrites scratch
    }
}

extern "C" void kernel_launch(void* const* d_in, const int* in_sizes, int n_in,
                              void* d_out, int out_size, void* d_ws, size_t ws_size,
                              hipStream_t stream)
{
    const float* input  = (const float*)d_in[0];
    const float* offset = (const float*)d_in[1];
    const float* w_off1 = (const float*)d_in[2];
    const float* b_off1 = (const float*)d_in[3];
    const float* w1     = (const float*)d_in[4];
    const float* b1     = (const float*)d_in[5];
    const float* w_off2 = (const float*)d_in[6];
    const float* b_off2 = (const float*)d_in[7];
    const float* w2     = (const float*)d_in[8];
    const float* b2     = (const float*)d_in[9];
    const float* w_last = (const float*)d_in[10];
    const float* b_last = (const float*)d_in[11];
    float* out = (float*)d_out;

    unsigned short* xn   = (unsigned short*)d_ws;          // 4,194,304 ush
    unsigned short* offn = xn + 4194304;                   // 2,097,152 ush
    unsigned short* x1n  = offn + 2097152;                 // 4,194,304 ush
    unsigned short* x2n  = x1n + 4194304;                  // 4,194,304 ush
    unsigned short* wfo  = x2n + 4194304;                  // 36,864 ush (two 27-oc sets)
    unsigned short* wf1  = wfo + 36864;                    // 36,864 ush
    unsigned short* wf2  = wf1 + 36864;                    // 36,864 ush
    unsigned short* wfl  = wf2 + 36864;                    // 36,864 ush
    float* bias54 = (float*)(wfl + 36864);                 // 64 f

    prep<<<dim3(1089), 256, 0, stream>>>(input, offset, w_off1, w_off2, b_off1, b_off2,
                                         w1, w2, w_last, xn, offn, wfo, wf1, wf2, wfl, bias54);

    // DCN 1 (fused offset-conv set 0, sliding 2-row blocks): sample xn, leaky -> x1n
    dcn_slide<0><<<dim3(512), 512, 0, stream>>>(xn, offn, wfo, bias54,
                                                wf1, b1, nullptr, x1n);
    // DCN 2 (fused offset-conv set 1): sample x1n, + xn residual (fp16 NHWC) -> x2n
    dcn_slide<1><<<dim3(512), 512, 0, stream>>>(x1n, offn, wfo + 18432, bias54 + 27,
                                                wf2, b2, xn, x2n);
    // final conv
    conv_stage64<<<dim3(1024), 512, 0, stream>>>(x2n, wfl, b_last, out);
}

// Round 20
// 80.894 us; speedup vs baseline: 2.1308x; 2.1308x over previous
//
#include <hip/hip_runtime.h>
#include <cmath>

#define HW   16384
#define Wd   128
#define Hd   128
#define NB   4

typedef __attribute__((ext_vector_type(8))) _Float16 h16x8;
typedef __attribute__((ext_vector_type(4))) float f32x4;
typedef __attribute__((ext_vector_type(4))) unsigned int u32x4;

__device__ inline unsigned short f2h(float f) {
    _Float16 h = (_Float16)f;
    return __builtin_bit_cast(unsigned short, h);
}
__device__ inline _Float16 u2h(unsigned short u) {
    return __builtin_bit_cast(_Float16, u);
}

// ---------- fused prep: weight repacks (fp16 MFMA A-frag layout) + bias + NHWC transposes ----------
__device__ inline void repack_one(int idx, const float* __restrict__ s1, const float* __restrict__ s2,
                                  int Osplit, int O, int CIN, int KS, unsigned short* __restrict__ dst) {
    int e    = idx & 7;
    int lane = (idx >> 3) & 63;
    int ks   = (idx >> 9) % KS;
    int m    = (idx / (512 * KS)) & 3;
    int k    = idx / (2048 * KS);
    int oc = m * 16 + (lane & 15);
    int c  = ks * 32 + (lane >> 4) * 8 + e;
    float v = 0.f;
    if (oc < O && c < CIN)
        v = (oc < Osplit) ? s1[((size_t)oc * CIN + c) * 9 + k]
                          : s2[((size_t)(oc - Osplit) * CIN + c) * 9 + k];
    dst[idx] = f2h(v);
}

__global__ __launch_bounds__(256) void prep(
    const float* __restrict__ input, const float* __restrict__ offset,
    const float* __restrict__ w_off1, const float* __restrict__ w_off2,
    const float* __restrict__ b_off1, const float* __restrict__ b_off2,
    const float* __restrict__ w1, const float* __restrict__ w2, const float* __restrict__ w_last,
    unsigned short* __restrict__ xn, unsigned short* __restrict__ offn,
    unsigned short* __restrict__ wfo, unsigned short* __restrict__ wf1,
    unsigned short* __restrict__ wf2, unsigned short* __restrict__ wfl,
    float* __restrict__ bias54)
{
    int blk = blockIdx.x;
    if (blk < 512) {
        int t = blk * 256 + threadIdx.x;
        if (t < 65536) {
            int b = t >> 14, p = t & 16383;
            const float* s = input + ((size_t)b * 64) * HW + p;
            unsigned short* d = xn + (size_t)t * 64;
#pragma unroll
            for (int g = 0; g < 8; g++) {
                unsigned short pk[8];
#pragma unroll
                for (int e = 0; e < 8; e++) pk[e] = f2h(s[(size_t)(g * 8 + e) * HW]);
                *(u32x4*)(d + g * 8) = *(u32x4*)pk;
            }
        } else {
            int u = t - 65536;
            int b = u >> 14, p = u & 16383;
            const float* s = offset + ((size_t)b * 32) * HW + p;
            unsigned short* d = offn + (size_t)u * 32;
#pragma unroll
            for (int g = 0; g < 4; g++) {
                unsigned short pk[8];
#pragma unroll
                for (int e = 0; e < 8; e++) pk[e] = f2h(s[(size_t)(g * 8 + e) * HW]);
                *(u32x4*)(d + g * 8) = *(u32x4*)pk;
            }
        }
    } else {
        int u = (blk - 512) * 256 + threadIdx.x;
        if (u < 18432)        repack_one(u, w_off1, w_off1, 27, 27, 32, 1, wfo);
        else if (u < 36864)   repack_one(u - 18432, w_off2, w_off2, 27, 27, 32, 1, wfo + 18432);
        else if (u < 73728)   repack_one(u - 36864, w1, w1, 64, 64, 64, 2, wf1);
        else if (u < 110592)  repack_one(u - 73728, w2, w2, 64, 64, 64, 2, wf2);
        else if (u < 147456)  repack_one(u - 110592, w_last, w_last, 64, 64, 64, 2, wfl);
        else if (u < 147510) {
            int j = u - 147456;
            bias54[j] = (j < 27) ? b_off1[j] : b_off2[j - 27];
        }
    }
}

// ---------- conv3x3 CIN=64 (final conv), LDS-staged window, 8 waves kh-split ----------
__global__ __launch_bounds__(512, 8) void conv_stage64(
    const unsigned short* __restrict__ xn, const unsigned short* __restrict__ wf,
    const float* __restrict__ bias, float* __restrict__ out)
{
    __shared__ __align__(16) unsigned short stage[198 * 64];   // 3x66 px x 64ch
    int lb = ((blockIdx.x & 7) << 7) | (blockIdx.x >> 3);
    int t = threadIdx.x;
    int pxbase = lb * 64;
    int b = pxbase >> 14;
    int pbase = pxbase & 16383;
    int rowbase = pbase >> 7, colbase = pbase & 127;
    const unsigned short* xb = xn + ((size_t)(b << 14)) * 64;

    for (int q = t; q < 1584; q += 512) {
        int ps = q >> 3, j = q & 7;
        int ly = ps / 66, lx = ps - ly * 66;
        int y = rowbase - 1 + ly, x = colbase - 1 + lx;
        bool ok = (y >= 0) & (y < Hd) & (x >= 0) & (x < Wd);
        u32x4 v = {0, 0, 0, 0};
        if (ok) v = *(const u32x4*)(xb + ((size_t)(y * Wd + x)) * 64 + j * 8);
        *(u32x4*)(stage + ps * 64 + ((j ^ (ps & 7)) << 3)) = v;
    }
    __syncthreads();

    int lane = t & 63;
    int wave = t >> 6;
    int kh = wave >> 2;
    int wv = wave & 3;
    int sp = wv * 16 + (lane & 15);
    int px = pxbase + sp;
    int p = px & 16383;
    int cg = lane >> 4;
    int cch = kh * 4 + cg;

    const h16x8* wfv = (const h16x8*)wf;
    f32x4 acc[4];
#pragma unroll
    for (int m = 0; m < 4; m++) acc[m] = (f32x4){0.f, 0.f, 0.f, 0.f};

#pragma unroll
    for (int k = 0; k < 9; k++) {
        int ps = (k / 3) * 66 + sp + (k % 3);
        h16x8 bq = *(const h16x8*)(stage + ps * 64 + ((cch ^ (ps & 7)) << 3));
        h16x8 aF[4];
#pragma unroll
        for (int m = 0; m < 4; m++)
            aF[m] = wfv[((k * 4 + m) * 2 + kh) * 64 + lane];
#pragma unroll
        for (int m = 0; m < 4; m++)
            acc[m] = __builtin_amdgcn_mfma_f32_16x16x32_f16(aF[m], bq, acc[m], 0, 0, 0);
    }

    __syncthreads();                 // stage reads done; red aliases stage
    float* red = (float*)stage;
    if (kh == 1) {
#pragma unroll
        for (int m = 0; m < 4; m++)
#pragma unroll
            for (int j = 0; j < 4; j++)
                red[(m * 4 + j) * 256 + wv * 64 + lane] = acc[m][j];
    }
    __syncthreads();
    if (kh == 0) {
#pragma unroll
        for (int m = 0; m < 4; m++) {
            int ocb = m * 16 + cg * 4;
#pragma unroll
            for (int r = 0; r < 4; r++) {
                int oc = ocb + r;
                float v = acc[m][r] + red[(m * 4 + r) * 256 + wv * 64 + lane] + bias[oc];
                out[((size_t)b * 64 + oc) * HW + p] = v;
            }
        }
    }
}

// ---------- DCNv2 sampling helpers ----------
struct Tap { float w00, w01, w10, w11; int o00, o01, o10, o11; };

__device__ inline Tap mkparams(float oy, float ox, float mv, int row, int col, int k) {
    Tap P;
    float mk = 1.f / (1.f + __expf(-mv));
    float ys = (float)(row + k / 3 - 1) + oy;
    float xs = (float)(col + k % 3 - 1) + ox;
    float y0f = floorf(ys), x0f = floorf(xs);
    float fy = ys - y0f, fx = xs - x0f;
    int y0 = (int)y0f, x0 = (int)x0f;
    int y1 = y0 + 1, x1 = x0 + 1;
    bool vy0 = (y0 >= 0) & (y0 < Hd);
    bool vy1 = (y1 >= 0) & (y1 < Hd);
    bool vx0 = (x0 >= 0) & (x0 < Wd);
    bool vx1 = (x1 >= 0) & (x1 < Wd);
    P.w00 = (vy0 && vx0) ? (1.f - fy) * (1.f - fx) * mk : 0.f;
    P.w01 = (vy0 && vx1) ? (1.f - fy) * fx * mk : 0.f;
    P.w10 = (vy1 && vx0) ? fy * (1.f - fx) * mk : 0.f;
    P.w11 = (vy1 && vx1) ? fy * fx * mk : 0.f;
    int iy0 = min(max(y0, 0), Hd - 1) * Wd;
    int iy1 = min(max(y1, 0), Hd - 1) * Wd;
    int ix0 = min(max(x0, 0), Wd - 1);
    int ix1 = min(max(x1, 0), Wd - 1);
    P.o00 = iy0 + ix0; P.o01 = iy0 + ix1; P.o10 = iy1 + ix0; P.o11 = iy1 + ix1;
    return P;
}

// ---------- DCNv2 with FUSED offset-conv (serial phases) + packed b128 tap table ----------
// tbl[s*4 + {0,1,2,3}] = {a01, a23, w01, w23}; one ds_read_b128 per tap in main loop.
// code = inw ? (ps<<3)|(ps&7) : 0x8000|o ; lds byte = ((code&0xFFF)^cch)<<4 ; fb o = code&0x7fff
// EPI 0: leaky -> outn. EPI 1: + residn (NHWC fp16) -> outn.
template<int EPI>
__global__ __launch_bounds__(512, 4) void dcn_fused(
    const unsigned short* __restrict__ xn, const unsigned short* __restrict__ offn,
    const unsigned short* __restrict__ wfo, const float* __restrict__ obias,
    const unsigned short* __restrict__ wf, const float* __restrict__ bias,
    const unsigned short* __restrict__ residn, unsigned short* __restrict__ outn)
{
    __shared__ __align__(16) unsigned short stage[490 * 64];  // 62.7KB main window
    __shared__ __align__(16) unsigned tbl[576 * 4];           // packed tap records (9.2KB)

    unsigned short* offstage = stage;           // 198*32 ush = 12672B (slots 0..98)
    float* omt = (float*)(stage + 6336);        // 27*64 f32 = 6912B (dead before main fill)

    int lb = ((blockIdx.x & 7) << 7) | (blockIdx.x >> 3);
    int t = threadIdx.x;
    int pxbase = lb * 64;
    int b = pxbase >> 14;
    int pbase = pxbase & 16383;
    int rowbase = pbase >> 7;
    int colbase = pbase & 127;
    int ybase = rowbase - 3;
    int xbase = colbase - 3;
    const unsigned short* xb = xn + ((size_t)(b << 14)) * 64;
    const unsigned short* ob = offn + ((size_t)(b << 14)) * 32;

    // ---- phase 0a: stage offn 3x66 window ----
    for (int q = t; q < 792; q += 512) {
        int ps = q >> 2, j = q & 3;
        int ly = ps / 66, lx = ps - ly * 66;
        int y = rowbase - 1 + ly, x = colbase - 1 + lx;
        bool ok = (y >= 0) & (y < Hd) & (x >= 0) & (x < Wd);
        u32x4 v = {0, 0, 0, 0};
        if (ok) v = *(const u32x4*)(ob + ((size_t)(y * Wd + x)) * 32 + j * 8);
        *(u32x4*)(offstage + ps * 32 + ((j ^ (ps & 3)) << 3)) = v;
    }
    __syncthreads();

    int lane = t & 63;
    int wave = t >> 6;

    // ---- phase 0b: offset conv, waves 0-3 (27 oc, m-tiles 0..1) ----
    if (wave < 4) {
        int osp = wave * 16 + (lane & 15);
        int cg4 = lane >> 4;
        const h16x8* wfv = (const h16x8*)wfo;
        f32x4 oacc[2];
#pragma unroll
        for (int m = 0; m < 2; m++) oacc[m] = (f32x4){0.f, 0.f, 0.f, 0.f};
#pragma unroll
        for (int k = 0; k < 9; k++) {
            int ps = (k / 3) * 66 + osp + (k % 3);
            h16x8 bq = *(const h16x8*)(offstage + ps * 32 + ((cg4 ^ (ps & 3)) << 3));
#pragma unroll
            for (int m = 0; m < 2; m++) {
                h16x8 aF = wfv[(k * 4 + m) * 64 + lane];
                oacc[m] = __builtin_amdgcn_mfma_f32_16x16x32_f16(aF, bq, oacc[m], 0, 0, 0);
            }
        }
#pragma unroll
        for (int m = 0; m < 2; m++) {
            int ocb = m * 16 + cg4 * 4;
#pragma unroll
            for (int r = 0; r < 4; r++) {
                int oc = ocb + r;
                if (oc < 27) omt[oc * 64 + osp] = oacc[m][r] + obias[oc];
            }
        }
    }
    __syncthreads();

    // ---- phase 1a: tap params from omt -> packed b128 records ----
    for (int s = t; s < 576; s += 512) {
        int k = s >> 6, sp2 = s & 63;
        int row = rowbase, col = colbase + sp2;
        float oy = omt[(2 * k) * 64 + sp2];
        float ox = omt[(2 * k + 1) * 64 + sp2];
        float mv = omt[(18 + k) * 64 + sp2];
        Tap P = mkparams(oy, ox, mv, row, col, k);

        unsigned a[4];
        int oo[4] = {P.o00, P.o01, P.o10, P.o11};
#pragma unroll
        for (int c = 0; c < 4; c++) {
            int o = oo[c];
            int y = o >> 7, x = o & 127;
            int ly = y - ybase, lx = x - xbase;
            bool inw = ((unsigned)ly < 7u) & ((unsigned)lx < 70u);
            int ps = min(max(ly, 0), 6) * 70 + min(max(lx, 0), 69);
            a[c] = inw ? (unsigned)((ps << 3) | (ps & 7)) : (0x8000u | (unsigned)o);
        }
        u32x4 pk4 = { a[0] | (a[1] << 16),
                      a[2] | (a[3] << 16),
                      (unsigned)f2h(P.w00) | ((unsigned)f2h(P.w01) << 16),
                      (unsigned)f2h(P.w10) | ((unsigned)f2h(P.w11) << 16) };
        *(u32x4*)&tbl[s * 4] = pk4;
    }
    __syncthreads();   // omt/offstage reads done; safe to overwrite stage

    // ---- phase 1b: fill main 7x70 stage ----
    for (int q = t; q < 3920; q += 512) {
        int ps = q >> 3, j = q & 7;
        int ly = ps / 70, lx = ps - ly * 70;
        int y = min(max(ybase + ly, 0), Hd - 1);
        int x = min(max(xbase + lx, 0), Wd - 1);
        u32x4 v = *(const u32x4*)(xb + ((size_t)(y * Wd + x)) * 64 + j * 8);
        *(u32x4*)(stage + ps * 64 + ((j ^ (ps & 7)) << 3)) = v;
    }
    __syncthreads();

    int kh = wave >> 2;
    int wv = wave & 3;
    int sp = wv * 16 + (lane & 15);
    int px = pxbase + sp;
    int cg = lane >> 4;
    int c0 = kh * 32 + cg * 8;
    int cch = kh * 4 + cg;

    const h16x8* wfv = (const h16x8*)wf;

    f32x4 acc[4];
#pragma unroll
    for (int m = 0; m < 4; m++) acc[m] = (f32x4){0.f, 0.f, 0.f, 0.f};

#pragma unroll
    for (int k = 0; k < 9; k++) {
        int s = k * 64 + sp;
        u32x4 tv = *(const u32x4*)&tbl[s * 4];
        unsigned a01 = tv[0], a23 = tv[1], w01 = tv[2], w23 = tv[3];

        unsigned code[4] = { a01 & 0xffffu, a01 >> 16, a23 & 0xffffu, a23 >> 16 };
        h16x8 gc[4];
#pragma unroll
        for (int c = 0; c < 4; c++)
            gc[c] = *(const h16x8*)((const char*)stage + (((code[c] & 0xFFFu) ^ (unsigned)cch) << 4));

        if (__builtin_expect((a01 | a23) & 0x80008000u, 0)) {
#pragma unroll
            for (int c = 0; c < 4; c++)
                if (code[c] & 0x8000u)
                    gc[c] = *(const h16x8*)(xb + (size_t)(code[c] & 0x7fffu) * 64 + c0);
        }

        _Float16 h00 = u2h((unsigned short)(w01 & 0xffffu));
        _Float16 h01 = u2h((unsigned short)(w01 >> 16));
        _Float16 h10 = u2h((unsigned short)(w23 & 0xffffu));
        _Float16 h11 = u2h((unsigned short)(w23 >> 16));
        h16x8 bF = gc[0] * h00;
        bF = gc[1] * h01 + bF;
        bF = gc[2] * h10 + bF;
        bF = gc[3] * h11 + bF;

        h16x8 aF[4];
#pragma unroll
        for (int m = 0; m < 4; m++)
            aF[m] = wfv[((k * 4 + m) * 2 + kh) * 64 + lane];
#pragma unroll
        for (int m = 0; m < 4; m++)
            acc[m] = __builtin_amdgcn_mfma_f32_16x16x32_f16(aF[m], bF, acc[m], 0, 0, 0);
    }

    __syncthreads();
    float* red = (float*)stage;
    if (kh == 1) {
#pragma unroll
        for (int m = 0; m < 4; m++)
#pragma unroll
            for (int j = 0; j < 4; j++)
                red[(m * 4 + j) * 256 + wv * 64 + lane] = acc[m][j];
    }
    __syncthreads();
    if (kh == 0) {
        unsigned short* drow = outn + (size_t)px * 64;
        const unsigned short* rrow = (EPI == 1) ? residn + (size_t)px * 64 : nullptr;
#pragma unroll
        for (int m = 0; m < 4; m++) {
            int ocb = m * 16 + cg * 4;
            float rv[4] = {0.f, 0.f, 0.f, 0.f};
            if (EPI == 1) {
                ushort4 rr = *(const ushort4*)(rrow + ocb);
                rv[0] = (float)u2h(rr.x); rv[1] = (float)u2h(rr.y);
                rv[2] = (float)u2h(rr.z); rv[3] = (float)u2h(rr.w);
            }
            unsigned short pk[4];
#pragma unroll
            for (int r = 0; r < 4; r++) {
                int oc = ocb + r;
                float v = acc[m][r] + red[(m * 4 + r) * 256 + wv * 64 + lane] + bias[oc];
                if (EPI == 0) v = (v >= 0.f) ? v : 0.01f * v;
                if (EPI == 1) v += rv[r];
                pk[r] = f2h(v);
            }
            *(ushort4*)(drow + ocb) = *(ushort4*)pk;
        }
    }
}

extern "C" void kernel_launch(void* const* d_in, const int* in_sizes, int n_in,
                              void* d_out, int out_size, void* d_ws, size_t ws_size,
                              hipStream_t stream)
{
    const float* input  = (const float*)d_in[0];
    const float* offset = (const float*)d_in[1];
    const float* w_off1 = (const float*)d_in[2];
    const float* b_off1 = (const float*)d_in[3];
    const float* w1     = (const float*)d_in[4];
    const float* b1     = (const float*)d_in[5];
    const float* w_off2 = (const float*)d_in[6];
    const float* b_off2 = (const float*)d_in[7];
    const float* w2     = (const float*)d_in[8];
    const float* b2     = (const float*)d_in[9];
    const float* w_last = (const float*)d_in[10];
    const float* b_last = (const float*)d_in[11];
    float* out = (float*)d_out;

    unsigned short* xn   = (unsigned short*)d_ws;          // 4,194,304 ush
    unsigned short* offn = xn + 4194304;                   // 2,097,152 ush
    unsigned short* x1n  = offn + 2097152;                 // 4,194,304 ush
    unsigned short* x2n  = x1n + 4194304;                  // 4,194,304 ush
    unsigned short* wfo  = x2n + 4194304;                  // 36,864 ush (two 27-oc sets)
    unsigned short* wf1  = wfo + 36864;                    // 36,864 ush
    unsigned short* wf2  = wf1 + 36864;                    // 36,864 ush
    unsigned short* wfl  = wf2 + 36864;                    // 36,864 ush
    float* bias54 = (float*)(wfl + 36864);                 // 64 f

    prep<<<dim3(1089), 256, 0, stream>>>(input, offset, w_off1, w_off2, b_off1, b_off2,
                                         w1, w2, w_last, xn, offn, wfo, wf1, wf2, wfl, bias54);

    // DCN 1 (fused offset-conv set 0): sample xn, leaky -> x1n
    dcn_fused<0><<<dim3(1024), 512, 0, stream>>>(xn, offn, wfo, bias54,
                                                 wf1, b1, nullptr, x1n);
    // DCN 2 (fused offset-conv set 1): sample x1n, + xn residual (fp16 NHWC) -> x2n
    dcn_fused<1><<<dim3(1024), 512, 0, stream>>>(x1n, offn, wfo + 18432, bias54 + 27,
                                                 wf2, b2, xn, x2n);
    // final conv
    conv_stage64<<<dim3(1024), 512, 0, stream>>>(x2n, wfl, b_last, out);
}

// Round 21
// 73.382 us; speedup vs baseline: 2.3489x; 1.1024x over previous
//
#include <hip/hip_runtime.h>
#include <cmath>

#define HW   16384
#define Wd   128
#define Hd   128
#define NB   4

typedef __attribute__((ext_vector_type(8))) _Float16 h16x8;
typedef __attribute__((ext_vector_type(4))) float f32x4;
typedef __attribute__((ext_vector_type(4))) unsigned int u32x4;

__device__ inline unsigned short f2h(float f) {
    _Float16 h = (_Float16)f;
    return __builtin_bit_cast(unsigned short, h);
}
__device__ inline _Float16 u2h(unsigned short u) {
    return __builtin_bit_cast(_Float16, u);
}

// ---------- fused prep: weight repacks (fp16 MFMA A-frag layout) + bias + NHWC transposes ----------
__device__ inline void repack_one(int idx, const float* __restrict__ s1, const float* __restrict__ s2,
                                  int Osplit, int O, int CIN, int KS, unsigned short* __restrict__ dst) {
    int e    = idx & 7;
    int lane = (idx >> 3) & 63;
    int ks   = (idx >> 9) % KS;
    int m    = (idx / (512 * KS)) & 3;
    int k    = idx / (2048 * KS);
    int oc = m * 16 + (lane & 15);
    int c  = ks * 32 + (lane >> 4) * 8 + e;
    float v = 0.f;
    if (oc < O && c < CIN)
        v = (oc < Osplit) ? s1[((size_t)oc * CIN + c) * 9 + k]
                          : s2[((size_t)(oc - Osplit) * CIN + c) * 9 + k];
    dst[idx] = f2h(v);
}

__global__ __launch_bounds__(256) void prep(
    const float* __restrict__ input, const float* __restrict__ offset,
    const float* __restrict__ w_off1, const float* __restrict__ w_off2,
    const float* __restrict__ b_off1, const float* __restrict__ b_off2,
    const float* __restrict__ w1, const float* __restrict__ w2, const float* __restrict__ w_last,
    unsigned short* __restrict__ xn, unsigned short* __restrict__ offn,
    unsigned short* __restrict__ wfo, unsigned short* __restrict__ wf1,
    unsigned short* __restrict__ wf2, unsigned short* __restrict__ wfl,
    float* __restrict__ bias54)
{
    int blk = blockIdx.x;
    if (blk < 512) {
        int t = blk * 256 + threadIdx.x;
        if (t < 65536) {
            int b = t >> 14, p = t & 16383;
            const float* s = input + ((size_t)b * 64) * HW + p;
            unsigned short* d = xn + (size_t)t * 64;
#pragma unroll
            for (int g = 0; g < 8; g++) {
                unsigned short pk[8];
#pragma unroll
                for (int e = 0; e < 8; e++) pk[e] = f2h(s[(size_t)(g * 8 + e) * HW]);
                *(u32x4*)(d + g * 8) = *(u32x4*)pk;
            }
        } else {
            int u = t - 65536;
            int b = u >> 14, p = u & 16383;
            const float* s = offset + ((size_t)b * 32) * HW + p;
            unsigned short* d = offn + (size_t)u * 32;
#pragma unroll
            for (int g = 0; g < 4; g++) {
                unsigned short pk[8];
#pragma unroll
                for (int e = 0; e < 8; e++) pk[e] = f2h(s[(size_t)(g * 8 + e) * HW]);
                *(u32x4*)(d + g * 8) = *(u32x4*)pk;
            }
        }
    } else {
        int u = (blk - 512) * 256 + threadIdx.x;
        if (u < 18432)        repack_one(u, w_off1, w_off1, 27, 27, 32, 1, wfo);
        else if (u < 36864)   repack_one(u - 18432, w_off2, w_off2, 27, 27, 32, 1, wfo + 18432);
        else if (u < 73728)   repack_one(u - 36864, w1, w1, 64, 64, 64, 2, wf1);
        else if (u < 110592)  repack_one(u - 73728, w2, w2, 64, 64, 64, 2, wf2);
        else if (u < 147456)  repack_one(u - 110592, w_last, w_last, 64, 64, 64, 2, wfl);
        else if (u < 147510) {
            int j = u - 147456;
            bias54[j] = (j < 27) ? b_off1[j] : b_off2[j - 27];
        }
    }
}

// ---------- conv3x3 CIN=64 (final conv), LDS-staged window, 8 waves kh-split ----------
__global__ __launch_bounds__(512, 8) void conv_stage64(
    const unsigned short* __restrict__ xn, const unsigned short* __restrict__ wf,
    const float* __restrict__ bias, float* __restrict__ out)
{
    __shared__ __align__(16) unsigned short stage[198 * 64];   // 3x66 px x 64ch
    int lb = ((blockIdx.x & 7) << 7) | (blockIdx.x >> 3);
    int t = threadIdx.x;
    int pxbase = lb * 64;
    int b = pxbase >> 14;
    int pbase = pxbase & 16383;
    int rowbase = pbase >> 7, colbase = pbase & 127;
    const unsigned short* xb = xn + ((size_t)(b << 14)) * 64;

    for (int q = t; q < 1584; q += 512) {
        int ps = q >> 3, j = q & 7;
        int ly = ps / 66, lx = ps - ly * 66;
        int y = rowbase - 1 + ly, x = colbase - 1 + lx;
        bool ok = (y >= 0) & (y < Hd) & (x >= 0) & (x < Wd);
        u32x4 v = {0, 0, 0, 0};
        if (ok) v = *(const u32x4*)(xb + ((size_t)(y * Wd + x)) * 64 + j * 8);
        *(u32x4*)(stage + ps * 64 + ((j ^ (ps & 7)) << 3)) = v;
    }
    __syncthreads();

    int lane = t & 63;
    int wave = t >> 6;
    int kh = wave >> 2;
    int wv = wave & 3;
    int sp = wv * 16 + (lane & 15);
    int px = pxbase + sp;
    int p = px & 16383;
    int cg = lane >> 4;
    int cch = kh * 4 + cg;

    const h16x8* wfv = (const h16x8*)wf;
    f32x4 acc[4];
#pragma unroll
    for (int m = 0; m < 4; m++) acc[m] = (f32x4){0.f, 0.f, 0.f, 0.f};

#pragma unroll
    for (int k = 0; k < 9; k++) {
        int ps = (k / 3) * 66 + sp + (k % 3);
        h16x8 bq = *(const h16x8*)(stage + ps * 64 + ((cch ^ (ps & 7)) << 3));
        h16x8 aF[4];
#pragma unroll
        for (int m = 0; m < 4; m++)
            aF[m] = wfv[((k * 4 + m) * 2 + kh) * 64 + lane];
#pragma unroll
        for (int m = 0; m < 4; m++)
            acc[m] = __builtin_amdgcn_mfma_f32_16x16x32_f16(aF[m], bq, acc[m], 0, 0, 0);
    }

    __syncthreads();                 // stage reads done; red aliases stage
    float* red = (float*)stage;
    if (kh == 1) {
#pragma unroll
        for (int m = 0; m < 4; m++)
#pragma unroll
            for (int j = 0; j < 4; j++)
                red[(m * 4 + j) * 256 + wv * 64 + lane] = acc[m][j];
    }
    __syncthreads();
    if (kh == 0) {
#pragma unroll
        for (int m = 0; m < 4; m++) {
            int ocb = m * 16 + cg * 4;
#pragma unroll
            for (int r = 0; r < 4; r++) {
                int oc = ocb + r;
                float v = acc[m][r] + red[(m * 4 + r) * 256 + wv * 64 + lane] + bias[oc];
                out[((size_t)b * 64 + oc) * HW + p] = v;
            }
        }
    }
}

// ---------- DCNv2 sampling helpers ----------
struct Tap { float w00, w01, w10, w11; int o00, o01, o10, o11; };

__device__ inline Tap mkparams(float oy, float ox, float mv, int row, int col, int k) {
    Tap P;
    float mk = 1.f / (1.f + __expf(-mv));
    float ys = (float)(row + k / 3 - 1) + oy;
    float xs = (float)(col + k % 3 - 1) + ox;
    float y0f = floorf(ys), x0f = floorf(xs);
    float fy = ys - y0f, fx = xs - x0f;
    int y0 = (int)y0f, x0 = (int)x0f;
    int y1 = y0 + 1, x1 = x0 + 1;
    bool vy0 = (y0 >= 0) & (y0 < Hd);
    bool vy1 = (y1 >= 0) & (y1 < Hd);
    bool vx0 = (x0 >= 0) & (x0 < Wd);
    bool vx1 = (x1 >= 0) & (x1 < Wd);
    P.w00 = (vy0 && vx0) ? (1.f - fy) * (1.f - fx) * mk : 0.f;
    P.w01 = (vy0 && vx1) ? (1.f - fy) * fx * mk : 0.f;
    P.w10 = (vy1 && vx0) ? fy * (1.f - fx) * mk : 0.f;
    P.w11 = (vy1 && vx1) ? fy * fx * mk : 0.f;
    int iy0 = min(max(y0, 0), Hd - 1) * Wd;
    int iy1 = min(max(y1, 0), Hd - 1) * Wd;
    int ix0 = min(max(x0, 0), Wd - 1);
    int ix1 = min(max(x1, 0), Wd - 1);
    P.o00 = iy0 + ix0; P.o01 = iy0 + ix1; P.o10 = iy1 + ix0; P.o11 = iy1 + ix1;
    return P;
}

// ---------- DCNv2 fused, 4x16 pixel tile (square halo: 10x22 window, 28.2KB) ----------
// Tile: 4 rows x 16 cols; waves: kh = wave>>2 (K-half), wv = wave&3 (tile row).
// Main window 10 rows x 22 cols x 64ch fp16; offn window 6 x 18 x 32ch.
// tbl[s*4+{0..3}] = {a01,a23,w01,w23}; code = inw ? (ps<<3)|(ps&7) : 0x8000|o (ps<2048)
// lds byte = ((code&0x7FF)^cch)<<4 (speculative reads bounded inside allocation).
// EPI 0: leaky -> outn. EPI 1: + residn (NHWC fp16) -> outn.
template<int EPI>
__global__ __launch_bounds__(512, 6) void dcn_fused(
    const unsigned short* __restrict__ xn, const unsigned short* __restrict__ offn,
    const unsigned short* __restrict__ wfo, const float* __restrict__ obias,
    const unsigned short* __restrict__ wf, const float* __restrict__ bias,
    const unsigned short* __restrict__ residn, unsigned short* __restrict__ outn)
{
    __shared__ __align__(16) unsigned short stage[220 * 64];  // 10x22 slots = 28160B
    __shared__ __align__(16) unsigned tbl[576 * 4];           // 9216B

    unsigned short* offstage = stage;           // 108*32 ush = 6912B (dead before main fill)
    float* omt = (float*)(stage + 3456);        // 27*64 f32 = 6912B  (bytes 6912..13823)

    int lb = ((blockIdx.x & 7) << 7) | (blockIdx.x >> 3);     // 1024, XCD swizzle
    int t = threadIdx.x;
    int b  = lb >> 8;                 // batch
    int rt = (lb >> 3) & 31;          // row tile
    int ct = lb & 7;                  // col tile
    int rowbase = rt << 2;
    int colbase = ct << 4;
    int ybase = rowbase - 3;
    int xbase = colbase - 3;
    const unsigned short* xb = xn + ((size_t)(b << 14)) * 64;
    const unsigned short* ob = offn + ((size_t)(b << 14)) * 32;

    // ---- phase 0a: stage offn 6x18 window ----
    for (int q = t; q < 432; q += 512) {
        int ps = q >> 2, j = q & 3;
        int ly = ps / 18, lx = ps - ly * 18;
        int y = rowbase - 1 + ly, x = colbase - 1 + lx;
        bool ok = (y >= 0) & (y < Hd) & (x >= 0) & (x < Wd);
        u32x4 v = {0, 0, 0, 0};
        if (ok) v = *(const u32x4*)(ob + ((size_t)(y * Wd + x)) * 32 + j * 8);
        *(u32x4*)(offstage + ps * 32 + ((j ^ (ps & 3)) << 3)) = v;
    }
    __syncthreads();

    int lane = t & 63;
    int wave = t >> 6;

    // ---- phase 0b: offset conv, waves 0-3 (27 oc, m-tiles 0..1); wave = tile row ----
    if (wave < 4) {
        int tr = wave, tc = lane & 15;
        int osp = tr * 16 + tc;
        int cg4 = lane >> 4;
        const h16x8* wfv = (const h16x8*)wfo;
        f32x4 oacc[2];
#pragma unroll
        for (int m = 0; m < 2; m++) oacc[m] = (f32x4){0.f, 0.f, 0.f, 0.f};
#pragma unroll
        for (int k = 0; k < 9; k++) {
            int ps = (tr + k / 3) * 18 + tc + (k % 3);
            h16x8 bq = *(const h16x8*)(offstage + ps * 32 + ((cg4 ^ (ps & 3)) << 3));
#pragma unroll
            for (int m = 0; m < 2; m++) {
                h16x8 aF = wfv[(k * 4 + m) * 64 + lane];
                oacc[m] = __builtin_amdgcn_mfma_f32_16x16x32_f16(aF, bq, oacc[m], 0, 0, 0);
            }
        }
#pragma unroll
        for (int m = 0; m < 2; m++) {
            int ocb = m * 16 + cg4 * 4;
#pragma unroll
            for (int r = 0; r < 4; r++) {
                int oc = ocb + r;
                if (oc < 27) omt[oc * 64 + osp] = oacc[m][r] + obias[oc];
            }
        }
    }
    __syncthreads();

    // ---- phase 1a: tap params from omt -> packed b128 records ----
    for (int s = t; s < 576; s += 512) {
        int k = s >> 6, sp2 = s & 63;
        int tr = sp2 >> 4, tc = sp2 & 15;
        int row = rowbase + tr, col = colbase + tc;
        float oy = omt[(2 * k) * 64 + sp2];
        float ox = omt[(2 * k + 1) * 64 + sp2];
        float mv = omt[(18 + k) * 64 + sp2];
        Tap P = mkparams(oy, ox, mv, row, col, k);

        unsigned a[4];
        int oo[4] = {P.o00, P.o01, P.o10, P.o11};
#pragma unroll
        for (int c = 0; c < 4; c++) {
            int o = oo[c];
            int y = o >> 7, x = o & 127;
            int ly = y - ybase, lx = x - xbase;
            bool inw = ((unsigned)ly < 10u) & ((unsigned)lx < 22u);
            int ps = min(max(ly, 0), 9) * 22 + min(max(lx, 0), 21);
            a[c] = inw ? (unsigned)((ps << 3) | (ps & 7)) : (0x8000u | (unsigned)o);
        }
        u32x4 pk4 = { a[0] | (a[1] << 16),
                      a[2] | (a[3] << 16),
                      (unsigned)f2h(P.w00) | ((unsigned)f2h(P.w01) << 16),
                      (unsigned)f2h(P.w10) | ((unsigned)f2h(P.w11) << 16) };
        *(u32x4*)&tbl[s * 4] = pk4;
    }
    __syncthreads();   // omt/offstage reads done; safe to overwrite stage

    // ---- phase 1b: fill main 10x22 stage ----
    for (int q = t; q < 1760; q += 512) {
        int ps = q >> 3, j = q & 7;
        int ly = ps / 22, lx = ps - ly * 22;
        int y = min(max(ybase + ly, 0), Hd - 1);
        int x = min(max(xbase + lx, 0), Wd - 1);
        u32x4 v = *(const u32x4*)(xb + ((size_t)(y * Wd + x)) * 64 + j * 8);
        *(u32x4*)(stage + ps * 64 + ((j ^ (ps & 7)) << 3)) = v;
    }
    __syncthreads();

    int kh = wave >> 2;
    int wv = wave & 3;                 // tile row
    int tc = lane & 15;                // tile col
    int sp = wv * 16 + tc;
    int cg = lane >> 4;
    int c0 = kh * 32 + cg * 8;
    int cch = kh * 4 + cg;

    const h16x8* wfv = (const h16x8*)wf;

    f32x4 acc[4];
#pragma unroll
    for (int m = 0; m < 4; m++) acc[m] = (f32x4){0.f, 0.f, 0.f, 0.f};

#pragma unroll
    for (int k = 0; k < 9; k++) {
        int s = k * 64 + sp;
        u32x4 tv = *(const u32x4*)&tbl[s * 4];
        unsigned a01 = tv[0], a23 = tv[1], w01 = tv[2], w23 = tv[3];

        unsigned code[4] = { a01 & 0xffffu, a01 >> 16, a23 & 0xffffu, a23 >> 16 };
        h16x8 gc[4];
#pragma unroll
        for (int c = 0; c < 4; c++)
            gc[c] = *(const h16x8*)((const char*)stage + (((code[c] & 0x7FFu) ^ (unsigned)cch) << 4));

        if (__builtin_expect((a01 | a23) & 0x80008000u, 0)) {
#pragma unroll
            for (int c = 0; c < 4; c++)
                if (code[c] & 0x8000u)
                    gc[c] = *(const h16x8*)(xb + (size_t)(code[c] & 0x7fffu) * 64 + c0);
        }

        _Float16 h00 = u2h((unsigned short)(w01 & 0xffffu));
        _Float16 h01 = u2h((unsigned short)(w01 >> 16));
        _Float16 h10 = u2h((unsigned short)(w23 & 0xffffu));
        _Float16 h11 = u2h((unsigned short)(w23 >> 16));
        h16x8 bF = gc[0] * h00;
        bF = gc[1] * h01 + bF;
        bF = gc[2] * h10 + bF;
        bF = gc[3] * h11 + bF;

        h16x8 aF[4];
#pragma unroll
        for (int m = 0; m < 4; m++)
            aF[m] = wfv[((k * 4 + m) * 2 + kh) * 64 + lane];
#pragma unroll
        for (int m = 0; m < 4; m++)
            acc[m] = __builtin_amdgcn_mfma_f32_16x16x32_f16(aF[m], bF, acc[m], 0, 0, 0);
    }

    __syncthreads();
    float* red = (float*)stage;
    if (kh == 1) {
#pragma unroll
        for (int m = 0; m < 4; m++)
#pragma unroll
            for (int j = 0; j < 4; j++)
                red[(m * 4 + j) * 256 + wv * 64 + lane] = acc[m][j];
    }
    __syncthreads();
    if (kh == 0) {
        int p = ((rowbase + wv) << 7) + colbase + tc;
        int px = (b << 14) + p;
        unsigned short* drow = outn + (size_t)px * 64;
        const unsigned short* rrow = (EPI == 1) ? residn + (size_t)px * 64 : nullptr;
#pragma unroll
        for (int m = 0; m < 4; m++) {
            int ocb = m * 16 + cg * 4;
            float rv[4] = {0.f, 0.f, 0.f, 0.f};
            if (EPI == 1) {
                ushort4 rr = *(const ushort4*)(rrow + ocb);
                rv[0] = (float)u2h(rr.x); rv[1] = (float)u2h(rr.y);
                rv[2] = (float)u2h(rr.z); rv[3] = (float)u2h(rr.w);
            }
            unsigned short pk[4];
#pragma unroll
            for (int r = 0; r < 4; r++) {
                int oc = ocb + r;
                float v = acc[m][r] + red[(m * 4 + r) * 256 + wv * 64 + lane] + bias[oc];
                if (EPI == 0) v = (v >= 0.f) ? v : 0.01f * v;
                if (EPI == 1) v += rv[r];
                pk[r] = f2h(v);
            }
            *(ushort4*)(drow + ocb) = *(ushort4*)pk;
        }
    }
}

extern "C" void kernel_launch(void* const* d_in, const int* in_sizes, int n_in,
                              void* d_out, int out_size, void* d_ws, size_t ws_size,
                              hipStream_t stream)
{
    const float* input  = (const float*)d_in[0];
    const float* offset = (const float*)d_in[1];
    const float* w_off1 = (const float*)d_in[2];
    const float* b_off1 = (const float*)d_in[3];
    const float* w1     = (const float*)d_in[4];
    const float* b1     = (const float*)d_in[5];
    const float* w_off2 = (const float*)d_in[6];
    const float* b_off2 = (const float*)d_in[7];
    const float* w2     = (const float*)d_in[8];
    const float* b2     = (const float*)d_in[9];
    const float* w_last = (const float*)d_in[10];
    const float* b_last = (const float*)d_in[11];
    float* out = (float*)d_out;

    unsigned short* xn   = (unsigned short*)d_ws;          // 4,194,304 ush
    unsigned short* offn = xn + 4194304;                   // 2,097,152 ush
    unsigned short* x1n  = offn + 2097152;                 // 4,194,304 ush
    unsigned short* x2n  = x1n + 4194304;                  // 4,194,304 ush
    unsigned short* wfo  = x2n + 4194304;                  // 36,864 ush (two 27-oc sets)
    unsigned short* wf1  = wfo + 36864;                    // 36,864 ush
    unsigned short* wf2  = wf1 + 36864;                    // 36,864 ush
    unsigned short* wfl  = wf2 + 36864;                    // 36,864 ush
    float* bias54 = (float*)(wfl + 36864);                 // 64 f

    prep<<<dim3(1089), 256, 0, stream>>>(input, offset, w_off1, w_off2, b_off1, b_off2,
                                         w1, w2, w_last, xn, offn, wfo, wf1, wf2, wfl, bias54);

    // DCN 1 (fused offset-conv set 0, 4x16 tiles): sample xn, leaky -> x1n
    dcn_fused<0><<<dim3(1024), 512, 0, stream>>>(xn, offn, wfo, bias54,
                                                 wf1, b1, nullptr, x1n);
    // DCN 2 (fused offset-conv set 1): sample x1n, + xn residual (fp16 NHWC) -> x2n
    dcn_fused<1><<<dim3(1024), 512, 0, stream>>>(x1n, offn, wfo + 18432, bias54 + 27,
                                                 wf2, b2, xn, x2n);
    // final conv
    conv_stage64<<<dim3(1024), 512, 0, stream>>>(x2n, wfl, b_last, out);
}

// Round 22
// 72.139 us; speedup vs baseline: 2.3894x; 1.0172x over previous
//
#include <hip/hip_runtime.h>
#include <cmath>

#define HW   16384
#define Wd   128
#define Hd   128
#define NB   4

typedef __attribute__((ext_vector_type(8))) _Float16 h16x8;
typedef __attribute__((ext_vector_type(4))) float f32x4;
typedef __attribute__((ext_vector_type(4))) unsigned int u32x4;

__device__ inline unsigned short f2h(float f) {
    _Float16 h = (_Float16)f;
    return __builtin_bit_cast(unsigned short, h);
}
__device__ inline _Float16 u2h(unsigned short u) {
    return __builtin_bit_cast(_Float16, u);
}

// ---------- fused prep: weight repacks (fp16 MFMA A-frag layout) + bias + NHWC transposes ----------
__device__ inline void repack_one(int idx, const float* __restrict__ s1, const float* __restrict__ s2,
                                  int Osplit, int O, int CIN, int KS, unsigned short* __restrict__ dst) {
    int e    = idx & 7;
    int lane = (idx >> 3) & 63;
    int ks   = (idx >> 9) % KS;
    int m    = (idx / (512 * KS)) & 3;
    int k    = idx / (2048 * KS);
    int oc = m * 16 + (lane & 15);
    int c  = ks * 32 + (lane >> 4) * 8 + e;
    float v = 0.f;
    if (oc < O && c < CIN)
        v = (oc < Osplit) ? s1[((size_t)oc * CIN + c) * 9 + k]
                          : s2[((size_t)(oc - Osplit) * CIN + c) * 9 + k];
    dst[idx] = f2h(v);
}

__global__ __launch_bounds__(256) void prep(
    const float* __restrict__ input, const float* __restrict__ offset,
    const float* __restrict__ w_off1, const float* __restrict__ w_off2,
    const float* __restrict__ b_off1, const float* __restrict__ b_off2,
    const float* __restrict__ w1, const float* __restrict__ w2, const float* __restrict__ w_last,
    unsigned short* __restrict__ xn, unsigned short* __restrict__ offn,
    unsigned short* __restrict__ wfo, unsigned short* __restrict__ wf1,
    unsigned short* __restrict__ wf2, unsigned short* __restrict__ wfl,
    float* __restrict__ bias54)
{
    int blk = blockIdx.x;
    if (blk < 512) {
        int t = blk * 256 + threadIdx.x;
        if (t < 65536) {
            int b = t >> 14, p = t & 16383;
            const float* s = input + ((size_t)b * 64) * HW + p;
            unsigned short* d = xn + (size_t)t * 64;
#pragma unroll
            for (int g = 0; g < 8; g++) {
                unsigned short pk[8];
#pragma unroll
                for (int e = 0; e < 8; e++) pk[e] = f2h(s[(size_t)(g * 8 + e) * HW]);
                *(u32x4*)(d + g * 8) = *(u32x4*)pk;
            }
        } else {
            int u = t - 65536;
            int b = u >> 14, p = u & 16383;
            const float* s = offset + ((size_t)b * 32) * HW + p;
            unsigned short* d = offn + (size_t)u * 32;
#pragma unroll
            for (int g = 0; g < 4; g++) {
                unsigned short pk[8];
#pragma unroll
                for (int e = 0; e < 8; e++) pk[e] = f2h(s[(size_t)(g * 8 + e) * HW]);
                *(u32x4*)(d + g * 8) = *(u32x4*)pk;
            }
        }
    } else {
        int u = (blk - 512) * 256 + threadIdx.x;
        if (u < 18432)        repack_one(u, w_off1, w_off1, 27, 27, 32, 1, wfo);
        else if (u < 36864)   repack_one(u - 18432, w_off2, w_off2, 27, 27, 32, 1, wfo + 18432);
        else if (u < 73728)   repack_one(u - 36864, w1, w1, 64, 64, 64, 2, wf1);
        else if (u < 110592)  repack_one(u - 73728, w2, w2, 64, 64, 64, 2, wf2);
        else if (u < 147456)  repack_one(u - 110592, w_last, w_last, 64, 64, 64, 2, wfl);
        else if (u < 147510) {
            int j = u - 147456;
            bias54[j] = (j < 27) ? b_off1[j] : b_off2[j - 27];
        }
    }
}

// ---------- conv3x3 CIN=64 (final conv), 4x16 tile, 6x18 halo, 8 waves kh-split ----------
__global__ __launch_bounds__(512, 8) void conv_tile64(
    const unsigned short* __restrict__ xn, const unsigned short* __restrict__ wf,
    const float* __restrict__ bias, float* __restrict__ out)
{
    __shared__ __align__(16) char lds[16384];          // stage 108*64 ush = 13824B; red 16384B (union)
    unsigned short* stage = (unsigned short*)lds;
    float* red = (float*)lds;

    int lb = ((blockIdx.x & 7) << 7) | (blockIdx.x >> 3);
    int t = threadIdx.x;
    int b  = lb >> 8;
    int rt = (lb >> 3) & 31;
    int ct = lb & 7;
    int rowbase = rt << 2;
    int colbase = ct << 4;
    const unsigned short* xb = xn + ((size_t)(b << 14)) * 64;

    // stage 6x18 window (zero-pad outside image)
    for (int q = t; q < 864; q += 512) {
        int ps = q >> 3, j = q & 7;
        int ly = ps / 18, lx = ps - ly * 18;
        int y = rowbase - 1 + ly, x = colbase - 1 + lx;
        bool ok = (y >= 0) & (y < Hd) & (x >= 0) & (x < Wd);
        u32x4 v = {0, 0, 0, 0};
        if (ok) v = *(const u32x4*)(xb + ((size_t)(y * Wd + x)) * 64 + j * 8);
        *(u32x4*)(stage + ps * 64 + ((j ^ (ps & 7)) << 3)) = v;
    }
    __syncthreads();

    int lane = t & 63;
    int wave = t >> 6;
    int kh = wave >> 2;
    int wv = wave & 3;                 // tile row
    int tc = lane & 15;                // tile col
    int cg = lane >> 4;
    int cch = kh * 4 + cg;

    const h16x8* wfv = (const h16x8*)wf;
    f32x4 acc[4];
#pragma unroll
    for (int m = 0; m < 4; m++) acc[m] = (f32x4){0.f, 0.f, 0.f, 0.f};

#pragma unroll
    for (int k = 0; k < 9; k++) {
        int ps = (wv + k / 3) * 18 + tc + (k % 3);
        h16x8 bq = *(const h16x8*)(stage + ps * 64 + ((cch ^ (ps & 7)) << 3));
        h16x8 aF[4];
#pragma unroll
        for (int m = 0; m < 4; m++)
            aF[m] = wfv[((k * 4 + m) * 2 + kh) * 64 + lane];
#pragma unroll
        for (int m = 0; m < 4; m++)
            acc[m] = __builtin_amdgcn_mfma_f32_16x16x32_f16(aF[m], bq, acc[m], 0, 0, 0);
    }

    __syncthreads();                 // stage reads done; red overlays lds
    if (kh == 1) {
#pragma unroll
        for (int m = 0; m < 4; m++)
#pragma unroll
            for (int j = 0; j < 4; j++)
                red[(m * 4 + j) * 256 + wv * 64 + lane] = acc[m][j];
    }
    __syncthreads();
    if (kh == 0) {
        int p = ((rowbase + wv) << 7) + colbase + tc;
#pragma unroll
        for (int m = 0; m < 4; m++) {
            int ocb = m * 16 + cg * 4;
#pragma unroll
            for (int r = 0; r < 4; r++) {
                int oc = ocb + r;
                float v = acc[m][r] + red[(m * 4 + r) * 256 + wv * 64 + lane] + bias[oc];
                out[((size_t)b * 64 + oc) * HW + p] = v;
            }
        }
    }
}

// ---------- DCNv2 sampling helpers ----------
struct Tap { float w00, w01, w10, w11; int o00, o01, o10, o11; };

__device__ inline Tap mkparams(float oy, float ox, float mv, int row, int col, int k) {
    Tap P;
    float mk = 1.f / (1.f + __expf(-mv));
    float ys = (float)(row + k / 3 - 1) + oy;
    float xs = (float)(col + k % 3 - 1) + ox;
    float y0f = floorf(ys), x0f = floorf(xs);
    float fy = ys - y0f, fx = xs - x0f;
    int y0 = (int)y0f, x0 = (int)x0f;
    int y1 = y0 + 1, x1 = x0 + 1;
    bool vy0 = (y0 >= 0) & (y0 < Hd);
    bool vy1 = (y1 >= 0) & (y1 < Hd);
    bool vx0 = (x0 >= 0) & (x0 < Wd);
    bool vx1 = (x1 >= 0) & (x1 < Wd);
    P.w00 = (vy0 && vx0) ? (1.f - fy) * (1.f - fx) * mk : 0.f;
    P.w01 = (vy0 && vx1) ? (1.f - fy) * fx * mk : 0.f;
    P.w10 = (vy1 && vx0) ? fy * (1.f - fx) * mk : 0.f;
    P.w11 = (vy1 && vx1) ? fy * fx * mk : 0.f;
    int iy0 = min(max(y0, 0), Hd - 1) * Wd;
    int iy1 = min(max(y1, 0), Hd - 1) * Wd;
    int ix0 = min(max(x0, 0), Wd - 1);
    int ix1 = min(max(x1, 0), Wd - 1);
    P.o00 = iy0 + ix0; P.o01 = iy0 + ix1; P.o10 = iy1 + ix0; P.o11 = iy1 + ix1;
    return P;
}

// ---------- DCNv2 fused, 4x16 pixel tile (square halo: 10x22 window, 28.2KB) ----------
// EPI 0: leaky -> outn. EPI 1: + residn (NHWC fp16) -> outn.
template<int EPI>
__global__ __launch_bounds__(512, 6) void dcn_fused(
    const unsigned short* __restrict__ xn, const unsigned short* __restrict__ offn,
    const unsigned short* __restrict__ wfo, const float* __restrict__ obias,
    const unsigned short* __restrict__ wf, const float* __restrict__ bias,
    const unsigned short* __restrict__ residn, unsigned short* __restrict__ outn)
{
    __shared__ __align__(16) unsigned short stage[220 * 64];  // 10x22 slots = 28160B
    __shared__ __align__(16) unsigned tbl[576 * 4];           // 9216B

    unsigned short* offstage = stage;           // 108*32 ush = 6912B (dead before main fill)
    float* omt = (float*)(stage + 3456);        // 27*64 f32 = 6912B  (bytes 6912..13823)

    int lb = ((blockIdx.x & 7) << 7) | (blockIdx.x >> 3);     // 1024, XCD swizzle
    int t = threadIdx.x;
    int b  = lb >> 8;                 // batch
    int rt = (lb >> 3) & 31;          // row tile
    int ct = lb & 7;                  // col tile
    int rowbase = rt << 2;
    int colbase = ct << 4;
    int ybase = rowbase - 3;
    int xbase = colbase - 3;
    const unsigned short* xb = xn + ((size_t)(b << 14)) * 64;
    const unsigned short* ob = offn + ((size_t)(b << 14)) * 32;

    // ---- phase 0a: stage offn 6x18 window ----
    for (int q = t; q < 432; q += 512) {
        int ps = q >> 2, j = q & 3;
        int ly = ps / 18, lx = ps - ly * 18;
        int y = rowbase - 1 + ly, x = colbase - 1 + lx;
        bool ok = (y >= 0) & (y < Hd) & (x >= 0) & (x < Wd);
        u32x4 v = {0, 0, 0, 0};
        if (ok) v = *(const u32x4*)(ob + ((size_t)(y * Wd + x)) * 32 + j * 8);
        *(u32x4*)(offstage + ps * 32 + ((j ^ (ps & 3)) << 3)) = v;
    }
    __syncthreads();

    int lane = t & 63;
    int wave = t >> 6;

    // ---- phase 0b: offset conv, waves 0-3 (27 oc, m-tiles 0..1); wave = tile row ----
    if (wave < 4) {
        int tr = wave, tc = lane & 15;
        int osp = tr * 16 + tc;
        int cg4 = lane >> 4;
        const h16x8* wfv = (const h16x8*)wfo;
        f32x4 oacc[2];
#pragma unroll
        for (int m = 0; m < 2; m++) oacc[m] = (f32x4){0.f, 0.f, 0.f, 0.f};
#pragma unroll
        for (int k = 0; k < 9; k++) {
            int ps = (tr + k / 3) * 18 + tc + (k % 3);
            h16x8 bq = *(const h16x8*)(offstage + ps * 32 + ((cg4 ^ (ps & 3)) << 3));
#pragma unroll
            for (int m = 0; m < 2; m++) {
                h16x8 aF = wfv[(k * 4 + m) * 64 + lane];
                oacc[m] = __builtin_amdgcn_mfma_f32_16x16x32_f16(aF, bq, oacc[m], 0, 0, 0);
            }
        }
#pragma unroll
        for (int m = 0; m < 2; m++) {
            int ocb = m * 16 + cg4 * 4;
#pragma unroll
            for (int r = 0; r < 4; r++) {
                int oc = ocb + r;
                if (oc < 27) omt[oc * 64 + osp] = oacc[m][r] + obias[oc];
            }
        }
    }
    __syncthreads();

    // ---- phase 1a: tap params from omt -> packed b128 records ----
    for (int s = t; s < 576; s += 512) {
        int k = s >> 6, sp2 = s & 63;
        int tr = sp2 >> 4, tc = sp2 & 15;
        int row = rowbase + tr, col = colbase + tc;
        float oy = omt[(2 * k) * 64 + sp2];
        float ox = omt[(2 * k + 1) * 64 + sp2];
        float mv = omt[(18 + k) * 64 + sp2];
        Tap P = mkparams(oy, ox, mv, row, col, k);

        unsigned a[4];
        int oo[4] = {P.o00, P.o01, P.o10, P.o11};
#pragma unroll
        for (int c = 0; c < 4; c++) {
            int o = oo[c];
            int y = o >> 7, x = o & 127;
            int ly = y - ybase, lx = x - xbase;
            bool inw = ((unsigned)ly < 10u) & ((unsigned)lx < 22u);
            int ps = min(max(ly, 0), 9) * 22 + min(max(lx, 0), 21);
            a[c] = inw ? (unsigned)((ps << 3) | (ps & 7)) : (0x8000u | (unsigned)o);
        }
        u32x4 pk4 = { a[0] | (a[1] << 16),
                      a[2] | (a[3] << 16),
                      (unsigned)f2h(P.w00) | ((unsigned)f2h(P.w01) << 16),
                      (unsigned)f2h(P.w10) | ((unsigned)f2h(P.w11) << 16) };
        *(u32x4*)&tbl[s * 4] = pk4;
    }
    __syncthreads();   // omt/offstage reads done; safe to overwrite stage

    // ---- phase 1b: fill main 10x22 stage ----
    for (int q = t; q < 1760; q += 512) {
        int ps = q >> 3, j = q & 7;
        int ly = ps / 22, lx = ps - ly * 22;
        int y = min(max(ybase + ly, 0), Hd - 1);
        int x = min(max(xbase + lx, 0), Wd - 1);
        u32x4 v = *(const u32x4*)(xb + ((size_t)(y * Wd + x)) * 64 + j * 8);
        *(u32x4*)(stage + ps * 64 + ((j ^ (ps & 7)) << 3)) = v;
    }
    __syncthreads();

    int kh = wave >> 2;
    int wv = wave & 3;                 // tile row
    int tc = lane & 15;                // tile col
    int sp = wv * 16 + tc;
    int cg = lane >> 4;
    int c0 = kh * 32 + cg * 8;
    int cch = kh * 4 + cg;

    const h16x8* wfv = (const h16x8*)wf;

    f32x4 acc[4];
#pragma unroll
    for (int m = 0; m < 4; m++) acc[m] = (f32x4){0.f, 0.f, 0.f, 0.f};

#pragma unroll
    for (int k = 0; k < 9; k++) {
        int s = k * 64 + sp;
        u32x4 tv = *(const u32x4*)&tbl[s * 4];
        unsigned a01 = tv[0], a23 = tv[1], w01 = tv[2], w23 = tv[3];

        unsigned code[4] = { a01 & 0xffffu, a01 >> 16, a23 & 0xffffu, a23 >> 16 };
        h16x8 gc[4];
#pragma unroll
        for (int c = 0; c < 4; c++)
            gc[c] = *(const h16x8*)((const char*)stage + (((code[c] & 0x7FFu) ^ (unsigned)cch) << 4));

        if (__builtin_expect((a01 | a23) & 0x80008000u, 0)) {
#pragma unroll
            for (int c = 0; c < 4; c++)
                if (code[c] & 0x8000u)
                    gc[c] = *(const h16x8*)(xb + (size_t)(code[c] & 0x7fffu) * 64 + c0);
        }

        _Float16 h00 = u2h((unsigned short)(w01 & 0xffffu));
        _Float16 h01 = u2h((unsigned short)(w01 >> 16));
        _Float16 h10 = u2h((unsigned short)(w23 & 0xffffu));
        _Float16 h11 = u2h((unsigned short)(w23 >> 16));
        h16x8 bF = gc[0] * h00;
        bF = gc[1] * h01 + bF;
        bF = gc[2] * h10 + bF;
        bF = gc[3] * h11 + bF;

        h16x8 aF[4];
#pragma unroll
        for (int m = 0; m < 4; m++)
            aF[m] = wfv[((k * 4 + m) * 2 + kh) * 64 + lane];
#pragma unroll
        for (int m = 0; m < 4; m++)
            acc[m] = __builtin_amdgcn_mfma_f32_16x16x32_f16(aF[m], bF, acc[m], 0, 0, 0);
    }

    __syncthreads();
    float* red = (float*)stage;
    if (kh == 1) {
#pragma unroll
        for (int m = 0; m < 4; m++)
#pragma unroll
            for (int j = 0; j < 4; j++)
                red[(m * 4 + j) * 256 + wv * 64 + lane] = acc[m][j];
    }
    __syncthreads();
    if (kh == 0) {
        int p = ((rowbase + wv) << 7) + colbase + tc;
        int px = (b << 14) + p;
        unsigned short* drow = outn + (size_t)px * 64;
        const unsigned short* rrow = (EPI == 1) ? residn + (size_t)px * 64 : nullptr;
#pragma unroll
        for (int m = 0; m < 4; m++) {
            int ocb = m * 16 + cg * 4;
            float rv[4] = {0.f, 0.f, 0.f, 0.f};
            if (EPI == 1) {
                ushort4 rr = *(const ushort4*)(rrow + ocb);
                rv[0] = (float)u2h(rr.x); rv[1] = (float)u2h(rr.y);
                rv[2] = (float)u2h(rr.z); rv[3] = (float)u2h(rr.w);
            }
            unsigned short pk[4];
#pragma unroll
            for (int r = 0; r < 4; r++) {
                int oc = ocb + r;
                float v = acc[m][r] + red[(m * 4 + r) * 256 + wv * 64 + lane] + bias[oc];
                if (EPI == 0) v = (v >= 0.f) ? v : 0.01f * v;
                if (EPI == 1) v += rv[r];
                pk[r] = f2h(v);
            }
            *(ushort4*)(drow + ocb) = *(ushort4*)pk;
        }
    }
}

extern "C" void kernel_launch(void* const* d_in, const int* in_sizes, int n_in,
                              void* d_out, int out_size, void* d_ws, size_t ws_size,
                              hipStream_t stream)
{
    const float* input  = (const float*)d_in[0];
    const float* offset = (const float*)d_in[1];
    const float* w_off1 = (const float*)d_in[2];
    const float* b_off1 = (const float*)d_in[3];
    const float* w1     = (const float*)d_in[4];
    const float* b1     = (const float*)d_in[5];
    const float* w_off2 = (const float*)d_in[6];
    const float* b_off2 = (const float*)d_in[7];
    const float* w2     = (const float*)d_in[8];
    const float* b2     = (const float*)d_in[9];
    const float* w_last = (const float*)d_in[10];
    const float* b_last = (const float*)d_in[11];
    float* out = (float*)d_out;

    unsigned short* xn   = (unsigned short*)d_ws;          // 4,194,304 ush
    unsigned short* offn = xn + 4194304;                   // 2,097,152 ush
    unsigned short* x1n  = offn + 2097152;                 // 4,194,304 ush
    unsigned short* x2n  = x1n + 4194304;                  // 4,194,304 ush
    unsigned short* wfo  = x2n + 4194304;                  // 36,864 ush (two 27-oc sets)
    unsigned short* wf1  = wfo + 36864;                    // 36,864 ush
    unsigned short* wf2  = wf1 + 36864;                    // 36,864 ush
    unsigned short* wfl  = wf2 + 36864;                    // 36,864 ush
    float* bias54 = (float*)(wfl + 36864);                 // 64 f

    prep<<<dim3(1089), 256, 0, stream>>>(input, offset, w_off1, w_off2, b_off1, b_off2,
                                         w1, w2, w_last, xn, offn, wfo, wf1, wf2, wfl, bias54);

    // DCN 1 (fused offset-conv set 0, 4x16 tiles): sample xn, leaky -> x1n
    dcn_fused<0><<<dim3(1024), 512, 0, stream>>>(xn, offn, wfo, bias54,
                                                 wf1, b1, nullptr, x1n);
    // DCN 2 (fused offset-conv set 1): sample x1n, + xn residual (fp16 NHWC) -> x2n
    dcn_fused<1><<<dim3(1024), 512, 0, stream>>>(x1n, offn, wfo + 18432, bias54 + 27,
                                                 wf2, b2, xn, x2n);
    // final conv (4x16 tiles)
    conv_tile64<<<dim3(1024), 512, 0, stream>>>(x2n, wfl, b_last, out);
}

// Round 23
// 71.309 us; speedup vs baseline: 2.4173x; 1.0116x over previous
//
#include <hip/hip_runtime.h>
#include <cmath>

#define HW   16384
#define Wd   128
#define Hd   128
#define NB   4

typedef __attribute__((ext_vector_type(8))) _Float16 h16x8;
typedef __attribute__((ext_vector_type(4))) float f32x4;
typedef __attribute__((ext_vector_type(4))) unsigned int u32x4;

__device__ inline unsigned short f2h(float f) {
    _Float16 h = (_Float16)f;
    return __builtin_bit_cast(unsigned short, h);
}
__device__ inline _Float16 u2h(unsigned short u) {
    return __builtin_bit_cast(_Float16, u);
}

// ---------- fused prep: weight repacks (fp16 MFMA A-frag layout) + bias + NHWC transposes ----------
__device__ inline void repack_one(int idx, const float* __restrict__ s1, const float* __restrict__ s2,
                                  int Osplit, int O, int CIN, int KS, unsigned short* __restrict__ dst) {
    int e    = idx & 7;
    int lane = (idx >> 3) & 63;
    int ks   = (idx >> 9) % KS;
    int m    = (idx / (512 * KS)) & 3;
    int k    = idx / (2048 * KS);
    int oc = m * 16 + (lane & 15);
    int c  = ks * 32 + (lane >> 4) * 8 + e;
    float v = 0.f;
    if (oc < O && c < CIN)
        v = (oc < Osplit) ? s1[((size_t)oc * CIN + c) * 9 + k]
                          : s2[((size_t)(oc - Osplit) * CIN + c) * 9 + k];
    dst[idx] = f2h(v);
}

__global__ __launch_bounds__(256) void prep(
    const float* __restrict__ input, const float* __restrict__ offset,
    const float* __restrict__ w_off1, const float* __restrict__ w_off2,
    const float* __restrict__ b_off1, const float* __restrict__ b_off2,
    const float* __restrict__ w1, const float* __restrict__ w2, const float* __restrict__ w_last,
    unsigned short* __restrict__ xn, unsigned short* __restrict__ offn,
    unsigned short* __restrict__ wfo, unsigned short* __restrict__ wf1,
    unsigned short* __restrict__ wf2, unsigned short* __restrict__ wfl,
    float* __restrict__ bias54)
{
    int blk = blockIdx.x;
    if (blk < 512) {
        int t = blk * 256 + threadIdx.x;
        if (t < 65536) {
            int b = t >> 14, p = t & 16383;
            const float* s = input + ((size_t)b * 64) * HW + p;
            unsigned short* d = xn + (size_t)t * 64;
#pragma unroll
            for (int g = 0; g < 8; g++) {
                unsigned short pk[8];
#pragma unroll
                for (int e = 0; e < 8; e++) pk[e] = f2h(s[(size_t)(g * 8 + e) * HW]);
                *(u32x4*)(d + g * 8) = *(u32x4*)pk;
            }
        } else {
            int u = t - 65536;
            int b = u >> 14, p = u & 16383;
            const float* s = offset + ((size_t)b * 32) * HW + p;
            unsigned short* d = offn + (size_t)u * 32;
#pragma unroll
            for (int g = 0; g < 4; g++) {
                unsigned short pk[8];
#pragma unroll
                for (int e = 0; e < 8; e++) pk[e] = f2h(s[(size_t)(g * 8 + e) * HW]);
                *(u32x4*)(d + g * 8) = *(u32x4*)pk;
            }
        }
    } else {
        int u = (blk - 512) * 256 + threadIdx.x;
        if (u < 18432)        repack_one(u, w_off1, w_off1, 27, 27, 32, 1, wfo);
        else if (u < 36864)   repack_one(u - 18432, w_off2, w_off2, 27, 27, 32, 1, wfo + 18432);
        else if (u < 73728)   repack_one(u - 36864, w1, w1, 64, 64, 64, 2, wf1);
        else if (u < 110592)  repack_one(u - 73728, w2, w2, 64, 64, 64, 2, wf2);
        else if (u < 147456)  repack_one(u - 110592, w_last, w_last, 64, 64, 64, 2, wfl);
        else if (u < 147510) {
            int j = u - 147456;
            bias54[j] = (j < 27) ? b_off1[j] : b_off2[j - 27];
        }
    }
}

// ---------- conv3x3 CIN=64 (final conv), 4x16 tile, 6x18 halo, 8 waves kh-split ----------
__global__ __launch_bounds__(512, 8) void conv_tile64(
    const unsigned short* __restrict__ xn, const unsigned short* __restrict__ wf,
    const float* __restrict__ bias, float* __restrict__ out)
{
    __shared__ __align__(16) char lds[16384];          // stage 108*64 ush = 13824B; red 16384B (union)
    unsigned short* stage = (unsigned short*)lds;
    float* red = (float*)lds;

    int lb = ((blockIdx.x & 7) << 7) | (blockIdx.x >> 3);
    int t = threadIdx.x;
    int b  = lb >> 8;
    int rt = (lb >> 3) & 31;
    int ct = lb & 7;
    int rowbase = rt << 2;
    int colbase = ct << 4;
    const unsigned short* xb = xn + ((size_t)(b << 14)) * 64;

    // stage 6x18 window (zero-pad outside image)
    for (int q = t; q < 864; q += 512) {
        int ps = q >> 3, j = q & 7;
        int ly = ps / 18, lx = ps - ly * 18;
        int y = rowbase - 1 + ly, x = colbase - 1 + lx;
        bool ok = (y >= 0) & (y < Hd) & (x >= 0) & (x < Wd);
        u32x4 v = {0, 0, 0, 0};
        if (ok) v = *(const u32x4*)(xb + ((size_t)(y * Wd + x)) * 64 + j * 8);
        *(u32x4*)(stage + ps * 64 + ((j ^ (ps & 7)) << 3)) = v;
    }
    __syncthreads();

    int lane = t & 63;
    int wave = t >> 6;
    int kh = wave >> 2;
    int wv = wave & 3;                 // tile row
    int tc = lane & 15;                // tile col
    int cg = lane >> 4;
    int cch = kh * 4 + cg;

    const h16x8* wfv = (const h16x8*)wf;
    f32x4 acc[4];
#pragma unroll
    for (int m = 0; m < 4; m++) acc[m] = (f32x4){0.f, 0.f, 0.f, 0.f};

#pragma unroll
    for (int k = 0; k < 9; k++) {
        int ps = (wv + k / 3) * 18 + tc + (k % 3);
        h16x8 bq = *(const h16x8*)(stage + ps * 64 + ((cch ^ (ps & 7)) << 3));
        h16x8 aF[4];
#pragma unroll
        for (int m = 0; m < 4; m++)
            aF[m] = wfv[((k * 4 + m) * 2 + kh) * 64 + lane];
#pragma unroll
        for (int m = 0; m < 4; m++)
            acc[m] = __builtin_amdgcn_mfma_f32_16x16x32_f16(aF[m], bq, acc[m], 0, 0, 0);
    }

    __syncthreads();                 // stage reads done; red overlays lds
    if (kh == 1) {
#pragma unroll
        for (int m = 0; m < 4; m++)
#pragma unroll
            for (int j = 0; j < 4; j++)
                red[(m * 4 + j) * 256 + wv * 64 + lane] = acc[m][j];
    }
    __syncthreads();
    if (kh == 0) {
        int p = ((rowbase + wv) << 7) + colbase + tc;
#pragma unroll
        for (int m = 0; m < 4; m++) {
            int ocb = m * 16 + cg * 4;
#pragma unroll
            for (int r = 0; r < 4; r++) {
                int oc = ocb + r;
                float v = acc[m][r] + red[(m * 4 + r) * 256 + wv * 64 + lane] + bias[oc];
                out[((size_t)b * 64 + oc) * HW + p] = v;
            }
        }
    }
}

// ---------- DCNv2 sampling helpers ----------
struct Tap { float w00, w01, w10, w11; int o00, o01, o10, o11; };

__device__ inline Tap mkparams(float oy, float ox, float mv, int row, int col, int k) {
    Tap P;
    float mk = 1.f / (1.f + __expf(-mv));
    float ys = (float)(row + k / 3 - 1) + oy;
    float xs = (float)(col + k % 3 - 1) + ox;
    float y0f = floorf(ys), x0f = floorf(xs);
    float fy = ys - y0f, fx = xs - x0f;
    int y0 = (int)y0f, x0 = (int)x0f;
    int y1 = y0 + 1, x1 = x0 + 1;
    bool vy0 = (y0 >= 0) & (y0 < Hd);
    bool vy1 = (y1 >= 0) & (y1 < Hd);
    bool vx0 = (x0 >= 0) & (x0 < Wd);
    bool vx1 = (x1 >= 0) & (x1 < Wd);
    P.w00 = (vy0 && vx0) ? (1.f - fy) * (1.f - fx) * mk : 0.f;
    P.w01 = (vy0 && vx1) ? (1.f - fy) * fx * mk : 0.f;
    P.w10 = (vy1 && vx0) ? fy * (1.f - fx) * mk : 0.f;
    P.w11 = (vy1 && vx1) ? fy * fx * mk : 0.f;
    int iy0 = min(max(y0, 0), Hd - 1) * Wd;
    int iy1 = min(max(y1, 0), Hd - 1) * Wd;
    int ix0 = min(max(x0, 0), Wd - 1);
    int ix1 = min(max(x1, 0), Wd - 1);
    P.o00 = iy0 + ix0; P.o01 = iy0 + ix1; P.o10 = iy1 + ix0; P.o11 = iy1 + ix1;
    return P;
}

// ---------- DCNv2 fused, 4x16 tile; DEDICATED offstage/omt; merged fill phase ----------
// LDS: stage 28160B + tbl 9216B + offstg 6912B + omt 6912B = 51200B -> 3 blocks/CU.
// Phase A: offn 6x18 fill + main 10x22 fill (one barrier, both streams in flight).
// B: offset conv (waves 0-3) -> omt. C: taps -> tbl. E: main loop. F: reduce. G: epilogue.
// code = inw ? (ps<<3)|(ps&7) : 0x8000|o ; lds byte = ((code&0x7FF)^cch)<<4.
// EPI 0: leaky -> outn. EPI 1: + residn (NHWC fp16) -> outn.
template<int EPI>
__global__ __launch_bounds__(512, 6) void dcn_fused(
    const unsigned short* __restrict__ xn, const unsigned short* __restrict__ offn,
    const unsigned short* __restrict__ wfo, const float* __restrict__ obias,
    const unsigned short* __restrict__ wf, const float* __restrict__ bias,
    const unsigned short* __restrict__ residn, unsigned short* __restrict__ outn)
{
    __shared__ __align__(16) unsigned short stage[220 * 64];  // 28160B (red aliases after main loop)
    __shared__ __align__(16) unsigned tbl[576 * 4];           // 9216B
    __shared__ __align__(16) unsigned short offstg[108 * 32]; // 6912B dedicated
    __shared__ __align__(16) float omt[27 * 64];              // 6912B dedicated

    int lb = ((blockIdx.x & 7) << 7) | (blockIdx.x >> 3);     // 1024, XCD swizzle
    int t = threadIdx.x;
    int b  = lb >> 8;                 // batch
    int rt = (lb >> 3) & 31;          // row tile
    int ct = lb & 7;                  // col tile
    int rowbase = rt << 2;
    int colbase = ct << 4;
    int ybase = rowbase - 3;
    int xbase = colbase - 3;
    const unsigned short* xb = xn + ((size_t)(b << 14)) * 64;
    const unsigned short* ob = offn + ((size_t)(b << 14)) * 32;

    // ---- phase A: offn 6x18 fill (432) + main 10x22 fill (1760) ----
    for (int q = t; q < 2192; q += 512) {
        if (q < 432) {
            int ps = q >> 2, j = q & 3;
            int ly = ps / 18, lx = ps - ly * 18;
            int y = rowbase - 1 + ly, x = colbase - 1 + lx;
            bool ok = (y >= 0) & (y < Hd) & (x >= 0) & (x < Wd);
            u32x4 v = {0, 0, 0, 0};
            if (ok) v = *(const u32x4*)(ob + ((size_t)(y * Wd + x)) * 32 + j * 8);
            *(u32x4*)(offstg + ps * 32 + ((j ^ (ps & 3)) << 3)) = v;
        } else {
            int qq = q - 432;
            int ps = qq >> 3, j = qq & 7;
            int ly = ps / 22, lx = ps - ly * 22;
            int y = min(max(ybase + ly, 0), Hd - 1);
            int x = min(max(xbase + lx, 0), Wd - 1);
            u32x4 v = *(const u32x4*)(xb + ((size_t)(y * Wd + x)) * 64 + j * 8);
            *(u32x4*)(stage + ps * 64 + ((j ^ (ps & 7)) << 3)) = v;
        }
    }
    __syncthreads();

    int lane = t & 63;
    int wave = t >> 6;

    // ---- phase B: offset conv, waves 0-3 (27 oc, m-tiles 0..1); wave = tile row ----
    if (wave < 4) {
        int tr = wave, tcl = lane & 15;
        int osp = tr * 16 + tcl;
        int cg4 = lane >> 4;
        const h16x8* wfv = (const h16x8*)wfo;
        f32x4 oacc[2];
#pragma unroll
        for (int m = 0; m < 2; m++) oacc[m] = (f32x4){0.f, 0.f, 0.f, 0.f};
#pragma unroll
        for (int k = 0; k < 9; k++) {
            int ps = (tr + k / 3) * 18 + tcl + (k % 3);
            h16x8 bq = *(const h16x8*)(offstg + ps * 32 + ((cg4 ^ (ps & 3)) << 3));
#pragma unroll
            for (int m = 0; m < 2; m++) {
                h16x8 aF = wfv[(k * 4 + m) * 64 + lane];
                oacc[m] = __builtin_amdgcn_mfma_f32_16x16x32_f16(aF, bq, oacc[m], 0, 0, 0);
            }
        }
#pragma unroll
        for (int m = 0; m < 2; m++) {
            int ocb = m * 16 + cg4 * 4;
#pragma unroll
            for (int r = 0; r < 4; r++) {
                int oc = ocb + r;
                if (oc < 27) omt[oc * 64 + osp] = oacc[m][r] + obias[oc];
            }
        }
    }
    __syncthreads();

    // ---- phase C: tap params from omt -> packed b128 records ----
    for (int s = t; s < 576; s += 512) {
        int k = s >> 6, sp2 = s & 63;
        int tr = sp2 >> 4, tcl = sp2 & 15;
        int row = rowbase + tr, col = colbase + tcl;
        float oy = omt[(2 * k) * 64 + sp2];
        float ox = omt[(2 * k + 1) * 64 + sp2];
        float mv = omt[(18 + k) * 64 + sp2];
        Tap P = mkparams(oy, ox, mv, row, col, k);

        unsigned a[4];
        int oo[4] = {P.o00, P.o01, P.o10, P.o11};
#pragma unroll
        for (int c = 0; c < 4; c++) {
            int o = oo[c];
            int y = o >> 7, x = o & 127;
            int ly = y - ybase, lx = x - xbase;
            bool inw = ((unsigned)ly < 10u) & ((unsigned)lx < 22u);
            int ps = min(max(ly, 0), 9) * 22 + min(max(lx, 0), 21);
            a[c] = inw ? (unsigned)((ps << 3) | (ps & 7)) : (0x8000u | (unsigned)o);
        }
        u32x4 pk4 = { a[0] | (a[1] << 16),
                      a[2] | (a[3] << 16),
                      (unsigned)f2h(P.w00) | ((unsigned)f2h(P.w01) << 16),
                      (unsigned)f2h(P.w10) | ((unsigned)f2h(P.w11) << 16) };
        *(u32x4*)&tbl[s * 4] = pk4;
    }
    __syncthreads();

    // ---- phase E: main loop ----
    int kh = wave >> 2;
    int wv = wave & 3;                 // tile row
    int tc = lane & 15;                // tile col
    int sp = wv * 16 + tc;
    int cg = lane >> 4;
    int c0 = kh * 32 + cg * 8;
    int cch = kh * 4 + cg;

    const h16x8* wfv = (const h16x8*)wf;

    f32x4 acc[4];
#pragma unroll
    for (int m = 0; m < 4; m++) acc[m] = (f32x4){0.f, 0.f, 0.f, 0.f};

#pragma unroll
    for (int k = 0; k < 9; k++) {
        int s = k * 64 + sp;
        u32x4 tv = *(const u32x4*)&tbl[s * 4];
        unsigned a01 = tv[0], a23 = tv[1], w01 = tv[2], w23 = tv[3];

        unsigned code[4] = { a01 & 0xffffu, a01 >> 16, a23 & 0xffffu, a23 >> 16 };
        h16x8 gc[4];
#pragma unroll
        for (int c = 0; c < 4; c++)
            gc[c] = *(const h16x8*)((const char*)stage + (((code[c] & 0x7FFu) ^ (unsigned)cch) << 4));

        if (__builtin_expect((a01 | a23) & 0x80008000u, 0)) {
#pragma unroll
            for (int c = 0; c < 4; c++)
                if (code[c] & 0x8000u)
                    gc[c] = *(const h16x8*)(xb + (size_t)(code[c] & 0x7fffu) * 64 + c0);
        }

        _Float16 h00 = u2h((unsigned short)(w01 & 0xffffu));
        _Float16 h01 = u2h((unsigned short)(w01 >> 16));
        _Float16 h10 = u2h((unsigned short)(w23 & 0xffffu));
        _Float16 h11 = u2h((unsigned short)(w23 >> 16));
        h16x8 bF = gc[0] * h00;
        bF = gc[1] * h01 + bF;
        bF = gc[2] * h10 + bF;
        bF = gc[3] * h11 + bF;

        h16x8 aF[4];
#pragma unroll
        for (int m = 0; m < 4; m++)
            aF[m] = wfv[((k * 4 + m) * 2 + kh) * 64 + lane];
#pragma unroll
        for (int m = 0; m < 4; m++)
            acc[m] = __builtin_amdgcn_mfma_f32_16x16x32_f16(aF[m], bF, acc[m], 0, 0, 0);
    }

    __syncthreads();
    float* red = (float*)stage;        // stage dead after main loop
    if (kh == 1) {
#pragma unroll
        for (int m = 0; m < 4; m++)
#pragma unroll
            for (int j = 0; j < 4; j++)
                red[(m * 4 + j) * 256 + wv * 64 + lane] = acc[m][j];
    }
    __syncthreads();
    if (kh == 0) {
        int p = ((rowbase + wv) << 7) + colbase + tc;
        int px = (b << 14) + p;
        unsigned short* drow = outn + (size_t)px * 64;
        const unsigned short* rrow = (EPI == 1) ? residn + (size_t)px * 64 : nullptr;
#pragma unroll
        for (int m = 0; m < 4; m++) {
            int ocb = m * 16 + cg * 4;
            float rv[4] = {0.f, 0.f, 0.f, 0.f};
            if (EPI == 1) {
                ushort4 rr = *(const ushort4*)(rrow + ocb);
                rv[0] = (float)u2h(rr.x); rv[1] = (float)u2h(rr.y);
                rv[2] = (float)u2h(rr.z); rv[3] = (float)u2h(rr.w);
            }
            unsigned short pk[4];
#pragma unroll
            for (int r = 0; r < 4; r++) {
                int oc = ocb + r;
                float v = acc[m][r] + red[(m * 4 + r) * 256 + wv * 64 + lane] + bias[oc];
                if (EPI == 0) v = (v >= 0.f) ? v : 0.01f * v;
                if (EPI == 1) v += rv[r];
                pk[r] = f2h(v);
            }
            *(ushort4*)(drow + ocb) = *(ushort4*)pk;
        }
    }
}

extern "C" void kernel_launch(void* const* d_in, const int* in_sizes, int n_in,
                              void* d_out, int out_size, void* d_ws, size_t ws_size,
                              hipStream_t stream)
{
    const float* input  = (const float*)d_in[0];
    const float* offset = (const float*)d_in[1];
    const float* w_off1 = (const float*)d_in[2];
    const float* b_off1 = (const float*)d_in[3];
    const float* w1     = (const float*)d_in[4];
    const float* b1     = (const float*)d_in[5];
    const float* w_off2 = (const float*)d_in[6];
    const float* b_off2 = (const float*)d_in[7];
    const float* w2     = (const float*)d_in[8];
    const float* b2     = (const float*)d_in[9];
    const float* w_last = (const float*)d_in[10];
    const float* b_last = (const float*)d_in[11];
    float* out = (float*)d_out;

    unsigned short* xn   = (unsigned short*)d_ws;          // 4,194,304 ush
    unsigned short* offn = xn + 4194304;                   // 2,097,152 ush
    unsigned short* x1n  = offn + 2097152;                 // 4,194,304 ush
    unsigned short* x2n  = x1n + 4194304;                  // 4,194,304 ush
    unsigned short* wfo  = x2n + 4194304;                  // 36,864 ush (two 27-oc sets)
    unsigned short* wf1  = wfo + 36864;                    // 36,864 ush
    unsigned short* wf2  = wf1 + 36864;                    // 36,864 ush
    unsigned short* wfl  = wf2 + 36864;                    // 36,864 ush
    float* bias54 = (float*)(wfl + 36864);                 // 64 f

    prep<<<dim3(1089), 256, 0, stream>>>(input, offset, w_off1, w_off2, b_off1, b_off2,
                                         w1, w2, w_last, xn, offn, wfo, wf1, wf2, wfl, bias54);

    // DCN 1 (fused offset-conv set 0, 4x16 tiles): sample xn, leaky -> x1n
    dcn_fused<0><<<dim3(1024), 512, 0, stream>>>(xn, offn, wfo, bias54,
                                                 wf1, b1, nullptr, x1n);
    // DCN 2 (fused offset-conv set 1): sample x1n, + xn residual (fp16 NHWC) -> x2n
    dcn_fused<1><<<dim3(1024), 512, 0, stream>>>(x1n, offn, wfo + 18432, bias54 + 27,
                                                 wf2, b2, xn, x2n);
    // final conv (4x16 tiles)
    conv_tile64<<<dim3(1024), 512, 0, stream>>>(x2n, wfl, b_last, out);
}

// Round 24
// 70.771 us; speedup vs baseline: 2.4356x; 1.0076x over previous
//
#include <hip/hip_runtime.h>
#include <cmath>

#define HW   16384
#define Wd   128
#define Hd   128
#define NB   4

typedef __attribute__((ext_vector_type(8))) _Float16 h16x8;
typedef __attribute__((ext_vector_type(4))) float f32x4;
typedef __attribute__((ext_vector_type(4))) unsigned int u32x4;

__device__ inline unsigned short f2h(float f) {
    _Float16 h = (_Float16)f;
    return __builtin_bit_cast(unsigned short, h);
}
__device__ inline _Float16 u2h(unsigned short u) {
    return __builtin_bit_cast(_Float16, u);
}

// ---------- fused prep: weight repacks (fp16 MFMA A-frag layout) + bias + NHWC transposes ----------
__device__ inline void repack_one(int idx, const float* __restrict__ s1, const float* __restrict__ s2,
                                  int Osplit, int O, int CIN, int KS, unsigned short* __restrict__ dst) {
    int e    = idx & 7;
    int lane = (idx >> 3) & 63;
    int ks   = (idx >> 9) % KS;
    int m    = (idx / (512 * KS)) & 3;
    int k    = idx / (2048 * KS);
    int oc = m * 16 + (lane & 15);
    int c  = ks * 32 + (lane >> 4) * 8 + e;
    float v = 0.f;
    if (oc < O && c < CIN)
        v = (oc < Osplit) ? s1[((size_t)oc * CIN + c) * 9 + k]
                          : s2[((size_t)(oc - Osplit) * CIN + c) * 9 + k];
    dst[idx] = f2h(v);
}

__global__ __launch_bounds__(256) void prep(
    const float* __restrict__ input, const float* __restrict__ offset,
    const float* __restrict__ w_off1, const float* __restrict__ w_off2,
    const float* __restrict__ b_off1, const float* __restrict__ b_off2,
    const float* __restrict__ w1, const float* __restrict__ w2, const float* __restrict__ w_last,
    unsigned short* __restrict__ xn, unsigned short* __restrict__ offn,
    unsigned short* __restrict__ wfo, unsigned short* __restrict__ wf1,
    unsigned short* __restrict__ wf2, unsigned short* __restrict__ wfl,
    float* __restrict__ bias54)
{
    int blk = blockIdx.x;
    if (blk < 512) {
        int t = blk * 256 + threadIdx.x;
        if (t < 65536) {
            int b = t >> 14, p = t & 16383;
            const float* s = input + ((size_t)b * 64) * HW + p;
            unsigned short* d = xn + (size_t)t * 64;
#pragma unroll
            for (int g = 0; g < 8; g++) {
                unsigned short pk[8];
#pragma unroll
                for (int e = 0; e < 8; e++) pk[e] = f2h(s[(size_t)(g * 8 + e) * HW]);
                *(u32x4*)(d + g * 8) = *(u32x4*)pk;
            }
        } else {
            int u = t - 65536;
            int b = u >> 14, p = u & 16383;
            const float* s = offset + ((size_t)b * 32) * HW + p;
            unsigned short* d = offn + (size_t)u * 32;
#pragma unroll
            for (int g = 0; g < 4; g++) {
                unsigned short pk[8];
#pragma unroll
                for (int e = 0; e < 8; e++) pk[e] = f2h(s[(size_t)(g * 8 + e) * HW]);
                *(u32x4*)(d + g * 8) = *(u32x4*)pk;
            }
        }
    } else {
        int u = (blk - 512) * 256 + threadIdx.x;
        if (u < 18432)        repack_one(u, w_off1, w_off1, 27, 27, 32, 1, wfo);
        else if (u < 36864)   repack_one(u - 18432, w_off2, w_off2, 27, 27, 32, 1, wfo + 18432);
        else if (u < 73728)   repack_one(u - 36864, w1, w1, 64, 64, 64, 2, wf1);
        else if (u < 110592)  repack_one(u - 73728, w2, w2, 64, 64, 64, 2, wf2);
        else if (u < 147456)  repack_one(u - 110592, w_last, w_last, 64, 64, 64, 2, wfl);
        else if (u < 147510) {
            int j = u - 147456;
            bias54[j] = (j < 27) ? b_off1[j] : b_off2[j - 27];
        }
    }
}

// ---------- conv3x3 CIN=64 (final conv), 4x16 tile, 6x18 halo, 8 waves kh-split ----------
__global__ __launch_bounds__(512, 8) void conv_tile64(
    const unsigned short* __restrict__ xn, const unsigned short* __restrict__ wf,
    const float* __restrict__ bias, float* __restrict__ out)
{
    __shared__ __align__(16) char lds[16384];          // stage 108*64 ush = 13824B; red 16384B (union)
    unsigned short* stage = (unsigned short*)lds;
    float* red = (float*)lds;

    int lb = ((blockIdx.x & 7) << 7) | (blockIdx.x >> 3);
    int t = threadIdx.x;
    int b  = lb >> 8;
    int rt = (lb >> 3) & 31;
    int ct = lb & 7;
    int rowbase = rt << 2;
    int colbase = ct << 4;
    const unsigned short* xb = xn + ((size_t)(b << 14)) * 64;

    // stage 6x18 window (zero-pad outside image)
    for (int q = t; q < 864; q += 512) {
        int ps = q >> 3, j = q & 7;
        int ly = ps / 18, lx = ps - ly * 18;
        int y = rowbase - 1 + ly, x = colbase - 1 + lx;
        bool ok = (y >= 0) & (y < Hd) & (x >= 0) & (x < Wd);
        u32x4 v = {0, 0, 0, 0};
        if (ok) v = *(const u32x4*)(xb + ((size_t)(y * Wd + x)) * 64 + j * 8);
        *(u32x4*)(stage + ps * 64 + ((j ^ (ps & 7)) << 3)) = v;
    }
    __syncthreads();

    int lane = t & 63;
    int wave = t >> 6;
    int kh = wave >> 2;
    int wv = wave & 3;                 // tile row
    int tc = lane & 15;                // tile col
    int cg = lane >> 4;
    int cch = kh * 4 + cg;

    const h16x8* wfv = (const h16x8*)wf;
    f32x4 acc[4];
#pragma unroll
    for (int m = 0; m < 4; m++) acc[m] = (f32x4){0.f, 0.f, 0.f, 0.f};

#pragma unroll
    for (int k = 0; k < 9; k++) {
        int ps = (wv + k / 3) * 18 + tc + (k % 3);
        h16x8 bq = *(const h16x8*)(stage + ps * 64 + ((cch ^ (ps & 7)) << 3));
        h16x8 aF[4];
#pragma unroll
        for (int m = 0; m < 4; m++)
            aF[m] = wfv[((k * 4 + m) * 2 + kh) * 64 + lane];
#pragma unroll
        for (int m = 0; m < 4; m++)
            acc[m] = __builtin_amdgcn_mfma_f32_16x16x32_f16(aF[m], bq, acc[m], 0, 0, 0);
    }

    __syncthreads();                 // stage reads done; red overlays lds
    if (kh == 1) {
#pragma unroll
        for (int m = 0; m < 4; m++)
#pragma unroll
            for (int j = 0; j < 4; j++)
                red[(m * 4 + j) * 256 + wv * 64 + lane] = acc[m][j];
    }
    __syncthreads();
    if (kh == 0) {
        int p = ((rowbase + wv) << 7) + colbase + tc;
#pragma unroll
        for (int m = 0; m < 4; m++) {
            int ocb = m * 16 + cg * 4;
#pragma unroll
            for (int r = 0; r < 4; r++) {
                int oc = ocb + r;
                float v = acc[m][r] + red[(m * 4 + r) * 256 + wv * 64 + lane] + bias[oc];
                out[((size_t)b * 64 + oc) * HW + p] = v;
            }
        }
    }
}

// ---------- DCNv2 sampling helpers ----------
struct Tap { float w00, w01, w10, w11; int o00, o01, o10, o11; };

__device__ inline Tap mkparams(float oy, float ox, float mv, int row, int col, int k) {
    Tap P;
    float mk = 1.f / (1.f + __expf(-mv));
    float ys = (float)(row + k / 3 - 1) + oy;
    float xs = (float)(col + k % 3 - 1) + ox;
    float y0f = floorf(ys), x0f = floorf(xs);
    float fy = ys - y0f, fx = xs - x0f;
    int y0 = (int)y0f, x0 = (int)x0f;
    int y1 = y0 + 1, x1 = x0 + 1;
    bool vy0 = (y0 >= 0) & (y0 < Hd);
    bool vy1 = (y1 >= 0) & (y1 < Hd);
    bool vx0 = (x0 >= 0) & (x0 < Wd);
    bool vx1 = (x1 >= 0) & (x1 < Wd);
    P.w00 = (vy0 && vx0) ? (1.f - fy) * (1.f - fx) * mk : 0.f;
    P.w01 = (vy0 && vx1) ? (1.f - fy) * fx * mk : 0.f;
    P.w10 = (vy1 && vx0) ? fy * (1.f - fx) * mk : 0.f;
    P.w11 = (vy1 && vx1) ? fy * fx * mk : 0.f;
    int iy0 = min(max(y0, 0), Hd - 1) * Wd;
    int iy1 = min(max(y1, 0), Hd - 1) * Wd;
    int ix0 = min(max(x0, 0), Wd - 1);
    int ix1 = min(max(x1, 0), Wd - 1);
    P.o00 = iy0 + ix0; P.o01 = iy0 + ix1; P.o10 = iy1 + ix0; P.o11 = iy1 + ix1;
    return P;
}

// ---------- DCNv2 fused, 4x16 tile; 8x20 window (|off|<1 in-window, ~0.3% fallback) ----------
// LDS: stage 20480B + tbl 9216B + offstg 6912B + omt(fp16) 3456B = 40064B.
// Phase A: offn 6x18 fill + main 8x20 fill. B: offset conv. C: taps. E: main. F: reduce. G: epi.
// code = inw ? (ps<<3)|(ps&7) : 0x8000|o ; lds byte = ((code&0x7FF)^cch)<<4
// (speculative fallback-lane probe <= 32KB, inside 40KB allocation; value discarded).
// EPI 0: leaky -> outn. EPI 1: + residn (NHWC fp16) -> outn.
template<int EPI>
__global__ __launch_bounds__(512, 6) void dcn_fused(
    const unsigned short* __restrict__ xn, const unsigned short* __restrict__ offn,
    const unsigned short* __restrict__ wfo, const float* __restrict__ obias,
    const unsigned short* __restrict__ wf, const float* __restrict__ bias,
    const unsigned short* __restrict__ residn, unsigned short* __restrict__ outn)
{
    __shared__ __align__(16) unsigned short stage[160 * 64];  // 8x20 slots = 20480B
    __shared__ __align__(16) unsigned tbl[576 * 4];           // 9216B
    __shared__ __align__(16) unsigned short offstg[108 * 32]; // 6912B dedicated
    __shared__ __align__(16) unsigned short omt[27 * 64];     // fp16, 3456B dedicated

    int lb = ((blockIdx.x & 7) << 7) | (blockIdx.x >> 3);     // 1024, XCD swizzle
    int t = threadIdx.x;
    int b  = lb >> 8;                 // batch
    int rt = (lb >> 3) & 31;          // row tile
    int ct = lb & 7;                  // col tile
    int rowbase = rt << 2;
    int colbase = ct << 4;
    int ybase = rowbase - 2;
    int xbase = colbase - 2;
    const unsigned short* xb = xn + ((size_t)(b << 14)) * 64;
    const unsigned short* ob = offn + ((size_t)(b << 14)) * 32;

    // ---- phase A: offn 6x18 fill (432) + main 8x20 fill (1280) ----
    for (int q = t; q < 1712; q += 512) {
        if (q < 432) {
            int ps = q >> 2, j = q & 3;
            int ly = ps / 18, lx = ps - ly * 18;
            int y = rowbase - 1 + ly, x = colbase - 1 + lx;
            bool ok = (y >= 0) & (y < Hd) & (x >= 0) & (x < Wd);
            u32x4 v = {0, 0, 0, 0};
            if (ok) v = *(const u32x4*)(ob + ((size_t)(y * Wd + x)) * 32 + j * 8);
            *(u32x4*)(offstg + ps * 32 + ((j ^ (ps & 3)) << 3)) = v;
        } else {
            int qq = q - 432;
            int ps = qq >> 3, j = qq & 7;
            int ly = ps / 20, lx = ps - ly * 20;
            int y = min(max(ybase + ly, 0), Hd - 1);
            int x = min(max(xbase + lx, 0), Wd - 1);
            u32x4 v = *(const u32x4*)(xb + ((size_t)(y * Wd + x)) * 64 + j * 8);
            *(u32x4*)(stage + ps * 64 + ((j ^ (ps & 7)) << 3)) = v;
        }
    }
    __syncthreads();

    int lane = t & 63;
    int wave = t >> 6;

    // ---- phase B: offset conv, waves 0-3 (27 oc, m-tiles 0..1); wave = tile row ----
    if (wave < 4) {
        int tr = wave, tcl = lane & 15;
        int osp = tr * 16 + tcl;
        int cg4 = lane >> 4;
        const h16x8* wfv = (const h16x8*)wfo;
        f32x4 oacc[2];
#pragma unroll
        for (int m = 0; m < 2; m++) oacc[m] = (f32x4){0.f, 0.f, 0.f, 0.f};
#pragma unroll
        for (int k = 0; k < 9; k++) {
            int ps = (tr + k / 3) * 18 + tcl + (k % 3);
            h16x8 bq = *(const h16x8*)(offstg + ps * 32 + ((cg4 ^ (ps & 3)) << 3));
#pragma unroll
            for (int m = 0; m < 2; m++) {
                h16x8 aF = wfv[(k * 4 + m) * 64 + lane];
                oacc[m] = __builtin_amdgcn_mfma_f32_16x16x32_f16(aF, bq, oacc[m], 0, 0, 0);
            }
        }
#pragma unroll
        for (int m = 0; m < 2; m++) {
            int ocb = m * 16 + cg4 * 4;
#pragma unroll
            for (int r = 0; r < 4; r++) {
                int oc = ocb + r;
                if (oc < 27) omt[oc * 64 + osp] = f2h(oacc[m][r] + obias[oc]);
            }
        }
    }
    __syncthreads();

    // ---- phase C: tap params from omt -> packed b128 records ----
    for (int s = t; s < 576; s += 512) {
        int k = s >> 6, sp2 = s & 63;
        int tr = sp2 >> 4, tcl = sp2 & 15;
        int row = rowbase + tr, col = colbase + tcl;
        float oy = (float)u2h(omt[(2 * k) * 64 + sp2]);
        float ox = (float)u2h(omt[(2 * k + 1) * 64 + sp2]);
        float mv = (float)u2h(omt[(18 + k) * 64 + sp2]);
        Tap P = mkparams(oy, ox, mv, row, col, k);

        unsigned a[4];
        int oo[4] = {P.o00, P.o01, P.o10, P.o11};
#pragma unroll
        for (int c = 0; c < 4; c++) {
            int o = oo[c];
            int y = o >> 7, x = o & 127;
            int ly = y - ybase, lx = x - xbase;
            bool inw = ((unsigned)ly < 8u) & ((unsigned)lx < 20u);
            int ps = min(max(ly, 0), 7) * 20 + min(max(lx, 0), 19);
            a[c] = inw ? (unsigned)((ps << 3) | (ps & 7)) : (0x8000u | (unsigned)o);
        }
        u32x4 pk4 = { a[0] | (a[1] << 16),
                      a[2] | (a[3] << 16),
                      (unsigned)f2h(P.w00) | ((unsigned)f2h(P.w01) << 16),
                      (unsigned)f2h(P.w10) | ((unsigned)f2h(P.w11) << 16) };
        *(u32x4*)&tbl[s * 4] = pk4;
    }
    __syncthreads();

    // ---- phase E: main loop ----
    int kh = wave >> 2;
    int wv = wave & 3;                 // tile row
    int tc = lane & 15;                // tile col
    int sp = wv * 16 + tc;
    int cg = lane >> 4;
    int c0 = kh * 32 + cg * 8;
    int cch = kh * 4 + cg;

    const h16x8* wfv = (const h16x8*)wf;

    f32x4 acc[4];
#pragma unroll
    for (int m = 0; m < 4; m++) acc[m] = (f32x4){0.f, 0.f, 0.f, 0.f};

#pragma unroll
    for (int k = 0; k < 9; k++) {
        int s = k * 64 + sp;
        u32x4 tv = *(const u32x4*)&tbl[s * 4];
        unsigned a01 = tv[0], a23 = tv[1], w01 = tv[2], w23 = tv[3];

        unsigned code[4] = { a01 & 0xffffu, a01 >> 16, a23 & 0xffffu, a23 >> 16 };
        h16x8 gc[4];
#pragma unroll
        for (int c = 0; c < 4; c++)
            gc[c] = *(const h16x8*)((const char*)stage + (((code[c] & 0x7FFu) ^ (unsigned)cch) << 4));

        if (__builtin_expect((a01 | a23) & 0x80008000u, 0)) {
#pragma unroll
            for (int c = 0; c < 4; c++)
                if (code[c] & 0x8000u)
                    gc[c] = *(const h16x8*)(xb + (size_t)(code[c] & 0x7fffu) * 64 + c0);
        }

        _Float16 h00 = u2h((unsigned short)(w01 & 0xffffu));
        _Float16 h01 = u2h((unsigned short)(w01 >> 16));
        _Float16 h10 = u2h((unsigned short)(w23 & 0xffffu));
        _Float16 h11 = u2h((unsigned short)(w23 >> 16));
        h16x8 bF = gc[0] * h00;
        bF = gc[1] * h01 + bF;
        bF = gc[2] * h10 + bF;
        bF = gc[3] * h11 + bF;

        h16x8 aF[4];
#pragma unroll
        for (int m = 0; m < 4; m++)
            aF[m] = wfv[((k * 4 + m) * 2 + kh) * 64 + lane];
#pragma unroll
        for (int m = 0; m < 4; m++)
            acc[m] = __builtin_amdgcn_mfma_f32_16x16x32_f16(aF[m], bF, acc[m], 0, 0, 0);
    }

    __syncthreads();
    float* red = (float*)stage;        // stage dead after main loop (16KB red fits in 20.5KB)
    if (kh == 1) {
#pragma unroll
        for (int m = 0; m < 4; m++)
#pragma unroll
            for (int j = 0; j < 4; j++)
                red[(m * 4 + j) * 256 + wv * 64 + lane] = acc[m][j];
    }
    __syncthreads();
    if (kh == 0) {
        int p = ((rowbase + wv) << 7) + colbase + tc;
        int px = (b << 14) + p;
        unsigned short* drow = outn + (size_t)px * 64;
        const unsigned short* rrow = (EPI == 1) ? residn + (size_t)px * 64 : nullptr;
#pragma unroll
        for (int m = 0; m < 4; m++) {
            int ocb = m * 16 + cg * 4;
            float rv[4] = {0.f, 0.f, 0.f, 0.f};
            if (EPI == 1) {
                ushort4 rr = *(const ushort4*)(rrow + ocb);
                rv[0] = (float)u2h(rr.x); rv[1] = (float)u2h(rr.y);
                rv[2] = (float)u2h(rr.z); rv[3] = (float)u2h(rr.w);
            }
            unsigned short pk[4];
#pragma unroll
            for (int r = 0; r < 4; r++) {
                int oc = ocb + r;
                float v = acc[m][r] + red[(m * 4 + r) * 256 + wv * 64 + lane] + bias[oc];
                if (EPI == 0) v = (v >= 0.f) ? v : 0.01f * v;
                if (EPI == 1) v += rv[r];
                pk[r] = f2h(v);
            }
            *(ushort4*)(drow + ocb) = *(ushort4*)pk;
        }
    }
}

extern "C" void kernel_launch(void* const* d_in, const int* in_sizes, int n_in,
                              void* d_out, int out_size, void* d_ws, size_t ws_size,
                              hipStream_t stream)
{
    const float* input  = (const float*)d_in[0];
    const float* offset = (const float*)d_in[1];
    const float* w_off1 = (const float*)d_in[2];
    const float* b_off1 = (const float*)d_in[3];
    const float* w1     = (const float*)d_in[4];
    const float* b1     = (const float*)d_in[5];
    const float* w_off2 = (const float*)d_in[6];
    const float* b_off2 = (const float*)d_in[7];
    const float* w2     = (const float*)d_in[8];
    const float* b2     = (const float*)d_in[9];
    const float* w_last = (const float*)d_in[10];
    const float* b_last = (const float*)d_in[11];
    float* out = (float*)d_out;

    unsigned short* xn   = (unsigned short*)d_ws;          // 4,194,304 ush
    unsigned short* offn = xn + 4194304;                   // 2,097,152 ush
    unsigned short* x1n  = offn + 2097152;                 // 4,194,304 ush
    unsigned short* x2n  = x1n + 4194304;                  // 4,194,304 ush
    unsigned short* wfo  = x2n + 4194304;                  // 36,864 ush (two 27-oc sets)
    unsigned short* wf1  = wfo + 36864;                    // 36,864 ush
    unsigned short* wf2  = wf1 + 36864;                    // 36,864 ush
    unsigned short* wfl  = wf2 + 36864;                    // 36,864 ush
    float* bias54 = (float*)(wfl + 36864);                 // 64 f

    prep<<<dim3(1089), 256, 0, stream>>>(input, offset, w_off1, w_off2, b_off1, b_off2,
                                         w1, w2, w_last, xn, offn, wfo, wf1, wf2, wfl, bias54);

    // DCN 1 (fused offset-conv set 0, 4x16 tiles, 8x20 window): sample xn, leaky -> x1n
    dcn_fused<0><<<dim3(1024), 512, 0, stream>>>(xn, offn, wfo, bias54,
                                                 wf1, b1, nullptr, x1n);
    // DCN 2 (fused offset-conv set 1): sample x1n, + xn residual (fp16 NHWC) -> x2n
    dcn_fused<1><<<dim3(1024), 512, 0, stream>>>(x1n, offn, wfo + 18432, bias54 + 27,
                                                 wf2, b2, xn, x2n);
    // final conv (4x16 tiles)
    conv_tile64<<<dim3(1024), 512, 0, stream>>>(x2n, wfl, b_last, out);
}

// Round 25
// 68.669 us; speedup vs baseline: 2.5102x; 1.0306x over previous
//
#include <hip/hip_runtime.h>
#include <cmath>

#define HW   16384
#define Wd   128
#define Hd   128
#define NB   4

typedef __attribute__((ext_vector_type(8))) _Float16 h16x8;
typedef __attribute__((ext_vector_type(4))) float f32x4;
typedef __attribute__((ext_vector_type(4))) unsigned int u32x4;

__device__ inline unsigned short f2h(float f) {
    _Float16 h = (_Float16)f;
    return __builtin_bit_cast(unsigned short, h);
}
__device__ inline _Float16 u2h(unsigned short u) {
    return __builtin_bit_cast(_Float16, u);
}

#define GLD_LDS(g, l) __builtin_amdgcn_global_load_lds( \
    (const __attribute__((address_space(1))) void*)(g), \
    (__attribute__((address_space(3))) void*)(l), 16, 0, 0)

// ---------- fused prep: weight repacks (fp16 MFMA A-frag layout) + bias + NHWC transposes ----------
__device__ inline void repack_one(int idx, const float* __restrict__ s1, const float* __restrict__ s2,
                                  int Osplit, int O, int CIN, int KS, unsigned short* __restrict__ dst) {
    int e    = idx & 7;
    int lane = (idx >> 3) & 63;
    int ks   = (idx >> 9) % KS;
    int m    = (idx / (512 * KS)) & 3;
    int k    = idx / (2048 * KS);
    int oc = m * 16 + (lane & 15);
    int c  = ks * 32 + (lane >> 4) * 8 + e;
    float v = 0.f;
    if (oc < O && c < CIN)
        v = (oc < Osplit) ? s1[((size_t)oc * CIN + c) * 9 + k]
                          : s2[((size_t)(oc - Osplit) * CIN + c) * 9 + k];
    dst[idx] = f2h(v);
}

__global__ __launch_bounds__(256) void prep(
    const float* __restrict__ input, const float* __restrict__ offset,
    const float* __restrict__ w_off1, const float* __restrict__ w_off2,
    const float* __restrict__ b_off1, const float* __restrict__ b_off2,
    const float* __restrict__ w1, const float* __restrict__ w2, const float* __restrict__ w_last,
    unsigned short* __restrict__ xn, unsigned short* __restrict__ offn,
    unsigned short* __restrict__ wfo, unsigned short* __restrict__ wf1,
    unsigned short* __restrict__ wf2, unsigned short* __restrict__ wfl,
    float* __restrict__ bias54)
{
    int blk = blockIdx.x;
    if (blk < 512) {
        int t = blk * 256 + threadIdx.x;
        if (t < 65536) {
            int b = t >> 14, p = t & 16383;
            const float* s = input + ((size_t)b * 64) * HW + p;
            unsigned short* d = xn + (size_t)t * 64;
#pragma unroll
            for (int g = 0; g < 8; g++) {
                unsigned short pk[8];
#pragma unroll
                for (int e = 0; e < 8; e++) pk[e] = f2h(s[(size_t)(g * 8 + e) * HW]);
                *(u32x4*)(d + g * 8) = *(u32x4*)pk;
            }
        } else {
            int u = t - 65536;
            int b = u >> 14, p = u & 16383;
            const float* s = offset + ((size_t)b * 32) * HW + p;
            unsigned short* d = offn + (size_t)u * 32;
#pragma unroll
            for (int g = 0; g < 4; g++) {
                unsigned short pk[8];
#pragma unroll
                for (int e = 0; e < 8; e++) pk[e] = f2h(s[(size_t)(g * 8 + e) * HW]);
                *(u32x4*)(d + g * 8) = *(u32x4*)pk;
            }
        }
    } else {
        int u = (blk - 512) * 256 + threadIdx.x;
        if (u < 18432)        repack_one(u, w_off1, w_off1, 27, 27, 32, 1, wfo);
        else if (u < 36864)   repack_one(u - 18432, w_off2, w_off2, 27, 27, 32, 1, wfo + 18432);
        else if (u < 73728)   repack_one(u - 36864, w1, w1, 64, 64, 64, 2, wf1);
        else if (u < 110592)  repack_one(u - 73728, w2, w2, 64, 64, 64, 2, wf2);
        else if (u < 147456)  repack_one(u - 110592, w_last, w_last, 64, 64, 64, 2, wfl);
        else if (u < 147510) {
            int j = u - 147456;
            bias54[j] = (j < 27) ? b_off1[j] : b_off2[j - 27];
        }
    }
}

// ---------- conv3x3 CIN=64 (final conv), 4x16 tile, 6x18 halo, global_load_lds staging ----------
// LDS linear in q (slot ps, chunk jj); global chunk j = jj^(ps&7); read formula unchanged.
__global__ __launch_bounds__(512, 8) void conv_tile64(
    const unsigned short* __restrict__ xn, const unsigned short* __restrict__ wf,
    const float* __restrict__ bias, float* __restrict__ out)
{
    __shared__ __align__(16) char lds[16384];          // stage 108*64 ush = 13824B; red 16384B (union)
    unsigned short* stage = (unsigned short*)lds;
    float* red = (float*)lds;

    int lb = ((blockIdx.x & 7) << 7) | (blockIdx.x >> 3);
    int t = threadIdx.x;
    int b  = lb >> 8;
    int rt = (lb >> 3) & 31;
    int ct = lb & 7;
    int rowbase = rt << 2;
    int colbase = ct << 4;
    const unsigned short* xb = xn + ((size_t)(b << 14)) * 64;
    int wv8 = t >> 6;

    // stage 6x18 window (zero-pad outside image), direct-to-LDS
#pragma unroll
    for (int pass = 0; pass < 2; ++pass) {
        int q = t + pass * 512;
        if (q < 864) {
            int ps = q >> 3, jj = q & 7;
            int j = jj ^ (ps & 7);
            int ly = ps / 18, lx = ps - ly * 18;
            int y = rowbase - 1 + ly, x = colbase - 1 + lx;
            bool ok = (y >= 0) & (y < Hd) & (x >= 0) & (x < Wd);
            if (ok) {
                const unsigned short* g = xb + ((size_t)(y * Wd + x)) * 64 + j * 8;
                char* lbase = (char*)stage + (size_t)(pass * 512 + wv8 * 64) * 16;
                GLD_LDS(g, lbase);
            } else {
                u32x4 z = {0, 0, 0, 0};
                *(u32x4*)((char*)stage + (size_t)q * 16) = z;
            }
        }
    }
    __syncthreads();

    int lane = t & 63;
    int wave = t >> 6;
    int kh = wave >> 2;
    int wv = wave & 3;                 // tile row
    int tc = lane & 15;                // tile col
    int cg = lane >> 4;
    int cch = kh * 4 + cg;

    const h16x8* wfv = (const h16x8*)wf;
    f32x4 acc[4];
#pragma unroll
    for (int m = 0; m < 4; m++) acc[m] = (f32x4){0.f, 0.f, 0.f, 0.f};

#pragma unroll
    for (int k = 0; k < 9; k++) {
        int ps = (wv + k / 3) * 18 + tc + (k % 3);
        h16x8 bq = *(const h16x8*)(stage + ps * 64 + ((cch ^ (ps & 7)) << 3));
        h16x8 aF[4];
#pragma unroll
        for (int m = 0; m < 4; m++)
            aF[m] = wfv[((k * 4 + m) * 2 + kh) * 64 + lane];
#pragma unroll
        for (int m = 0; m < 4; m++)
            acc[m] = __builtin_amdgcn_mfma_f32_16x16x32_f16(aF[m], bq, acc[m], 0, 0, 0);
    }

    __syncthreads();                 // stage reads done; red overlays lds
    if (kh == 1) {
#pragma unroll
        for (int m = 0; m < 4; m++)
#pragma unroll
            for (int j = 0; j < 4; j++)
                red[(m * 4 + j) * 256 + wv * 64 + lane] = acc[m][j];
    }
    __syncthreads();
    if (kh == 0) {
        int p = ((rowbase + wv) << 7) + colbase + tc;
#pragma unroll
        for (int m = 0; m < 4; m++) {
            int ocb = m * 16 + cg * 4;
#pragma unroll
            for (int r = 0; r < 4; r++) {
                int oc = ocb + r;
                float v = acc[m][r] + red[(m * 4 + r) * 256 + wv * 64 + lane] + bias[oc];
                out[((size_t)b * 64 + oc) * HW + p] = v;
            }
        }
    }
}

// ---------- DCNv2 sampling helpers ----------
struct Tap { float w00, w01, w10, w11; int o00, o01, o10, o11; };

__device__ inline Tap mkparams(float oy, float ox, float mv, int row, int col, int k) {
    Tap P;
    float mk = 1.f / (1.f + __expf(-mv));
    float ys = (float)(row + k / 3 - 1) + oy;
    float xs = (float)(col + k % 3 - 1) + ox;
    float y0f = floorf(ys), x0f = floorf(xs);
    float fy = ys - y0f, fx = xs - x0f;
    int y0 = (int)y0f, x0 = (int)x0f;
    int y1 = y0 + 1, x1 = x0 + 1;
    bool vy0 = (y0 >= 0) & (y0 < Hd);
    bool vy1 = (y1 >= 0) & (y1 < Hd);
    bool vx0 = (x0 >= 0) & (x0 < Wd);
    bool vx1 = (x1 >= 0) & (x1 < Wd);
    P.w00 = (vy0 && vx0) ? (1.f - fy) * (1.f - fx) * mk : 0.f;
    P.w01 = (vy0 && vx1) ? (1.f - fy) * fx * mk : 0.f;
    P.w10 = (vy1 && vx0) ? fy * (1.f - fx) * mk : 0.f;
    P.w11 = (vy1 && vx1) ? fy * fx * mk : 0.f;
    int iy0 = min(max(y0, 0), Hd - 1) * Wd;
    int iy1 = min(max(y1, 0), Hd - 1) * Wd;
    int ix0 = min(max(x0, 0), Wd - 1);
    int ix1 = min(max(x1, 0), Wd - 1);
    P.o00 = iy0 + ix0; P.o01 = iy0 + ix1; P.o10 = iy1 + ix0; P.o11 = iy1 + ix1;
    return P;
}

// ---------- DCNv2 fused, 4x16 tile; 8x20 window; global_load_lds staging ----------
// LDS linear in q; swizzle moved to global chunk index (j = jj^(ps&N)); reads unchanged.
// EPI 0: leaky -> outn. EPI 1: + residn (NHWC fp16) -> outn.
template<int EPI>
__global__ __launch_bounds__(512, 6) void dcn_fused(
    const unsigned short* __restrict__ xn, const unsigned short* __restrict__ offn,
    const unsigned short* __restrict__ wfo, const float* __restrict__ obias,
    const unsigned short* __restrict__ wf, const float* __restrict__ bias,
    const unsigned short* __restrict__ residn, unsigned short* __restrict__ outn)
{
    __shared__ __align__(16) unsigned short stage[160 * 64];  // 8x20 slots = 20480B
    __shared__ __align__(16) unsigned tbl[576 * 4];           // 9216B
    __shared__ __align__(16) unsigned short offstg[108 * 32]; // 6912B dedicated
    __shared__ __align__(16) unsigned short omt[27 * 64];     // fp16, 3456B dedicated

    int lb = ((blockIdx.x & 7) << 7) | (blockIdx.x >> 3);     // 1024, XCD swizzle
    int t = threadIdx.x;
    int b  = lb >> 8;                 // batch
    int rt = (lb >> 3) & 31;          // row tile
    int ct = lb & 7;                  // col tile
    int rowbase = rt << 2;
    int colbase = ct << 4;
    int ybase = rowbase - 2;
    int xbase = colbase - 2;
    const unsigned short* xb = xn + ((size_t)(b << 14)) * 64;
    const unsigned short* ob = offn + ((size_t)(b << 14)) * 32;
    int wv8 = t >> 6;

    // ---- phase A: offn 6x18 (432 chunks) + main 8x20 (1280 chunks), direct-to-LDS ----
    {
        int q = t;
        if (q < 432) {
            int ps = q >> 2, jj = q & 3;
            int j = jj ^ (ps & 3);
            int ly = ps / 18, lx = ps - ly * 18;
            int y = rowbase - 1 + ly, x = colbase - 1 + lx;
            bool ok = (y >= 0) & (y < Hd) & (x >= 0) & (x < Wd);
            if (ok) {
                const unsigned short* g = ob + ((size_t)(y * Wd + x)) * 32 + j * 8;
                char* lbase = (char*)offstg + (size_t)(wv8 * 64) * 16;
                GLD_LDS(g, lbase);
            } else {
                u32x4 z = {0, 0, 0, 0};
                *(u32x4*)((char*)offstg + (size_t)q * 16) = z;
            }
        }
    }
#pragma unroll
    for (int pass = 0; pass < 3; ++pass) {
        int q = t + pass * 512;
        if (q < 1280) {
            int ps = q >> 3, jj = q & 7;
            int j = jj ^ (ps & 7);
            int ly = ps / 20, lx = ps - ly * 20;
            int y = min(max(ybase + ly, 0), Hd - 1);
            int x = min(max(xbase + lx, 0), Wd - 1);
            const unsigned short* g = xb + ((size_t)(y * Wd + x)) * 64 + j * 8;
            char* lbase = (char*)stage + (size_t)(pass * 512 + wv8 * 64) * 16;
            GLD_LDS(g, lbase);
        }
    }
    __syncthreads();

    int lane = t & 63;
    int wave = t >> 6;

    // ---- phase B: offset conv, waves 0-3 (27 oc, m-tiles 0..1); wave = tile row ----
    if (wave < 4) {
        int tr = wave, tcl = lane & 15;
        int osp = tr * 16 + tcl;
        int cg4 = lane >> 4;
        const h16x8* wfv = (const h16x8*)wfo;
        f32x4 oacc[2];
#pragma unroll
        for (int m = 0; m < 2; m++) oacc[m] = (f32x4){0.f, 0.f, 0.f, 0.f};
#pragma unroll
        for (int k = 0; k < 9; k++) {
            int ps = (tr + k / 3) * 18 + tcl + (k % 3);
            h16x8 bq = *(const h16x8*)(offstg + ps * 32 + ((cg4 ^ (ps & 3)) << 3));
#pragma unroll
            for (int m = 0; m < 2; m++) {
                h16x8 aF = wfv[(k * 4 + m) * 64 + lane];
                oacc[m] = __builtin_amdgcn_mfma_f32_16x16x32_f16(aF, bq, oacc[m], 0, 0, 0);
            }
        }
#pragma unroll
        for (int m = 0; m < 2; m++) {
            int ocb = m * 16 + cg4 * 4;
#pragma unroll
            for (int r = 0; r < 4; r++) {
                int oc = ocb + r;
                if (oc < 27) omt[oc * 64 + osp] = f2h(oacc[m][r] + obias[oc]);
            }
        }
    }
    __syncthreads();

    // ---- phase C: tap params from omt -> packed b128 records ----
    for (int s = t; s < 576; s += 512) {
        int k = s >> 6, sp2 = s & 63;
        int tr = sp2 >> 4, tcl = sp2 & 15;
        int row = rowbase + tr, col = colbase + tcl;
        float oy = (float)u2h(omt[(2 * k) * 64 + sp2]);
        float ox = (float)u2h(omt[(2 * k + 1) * 64 + sp2]);
        float mv = (float)u2h(omt[(18 + k) * 64 + sp2]);
        Tap P = mkparams(oy, ox, mv, row, col, k);

        unsigned a[4];
        int oo[4] = {P.o00, P.o01, P.o10, P.o11};
#pragma unroll
        for (int c = 0; c < 4; c++) {
            int o = oo[c];
            int y = o >> 7, x = o & 127;
            int ly = y - ybase, lx = x - xbase;
            bool inw = ((unsigned)ly < 8u) & ((unsigned)lx < 20u);
            int ps = min(max(ly, 0), 7) * 20 + min(max(lx, 0), 19);
            a[c] = inw ? (unsigned)((ps << 3) | (ps & 7)) : (0x8000u | (unsigned)o);
        }
        u32x4 pk4 = { a[0] | (a[1] << 16),
                      a[2] | (a[3] << 16),
                      (unsigned)f2h(P.w00) | ((unsigned)f2h(P.w01) << 16),
                      (unsigned)f2h(P.w10) | ((unsigned)f2h(P.w11) << 16) };
        *(u32x4*)&tbl[s * 4] = pk4;
    }
    __syncthreads();

    // ---- phase E: main loop ----
    int kh = wave >> 2;
    int wv = wave & 3;                 // tile row
    int tc = lane & 15;                // tile col
    int sp = wv * 16 + tc;
    int cg = lane >> 4;
    int c0 = kh * 32 + cg * 8;
    int cch = kh * 4 + cg;

    const h16x8* wfv = (const h16x8*)wf;

    f32x4 acc[4];
#pragma unroll
    for (int m = 0; m < 4; m++) acc[m] = (f32x4){0.f, 0.f, 0.f, 0.f};

#pragma unroll
    for (int k = 0; k < 9; k++) {
        int s = k * 64 + sp;
        u32x4 tv = *(const u32x4*)&tbl[s * 4];
        unsigned a01 = tv[0], a23 = tv[1], w01 = tv[2], w23 = tv[3];

        unsigned code[4] = { a01 & 0xffffu, a01 >> 16, a23 & 0xffffu, a23 >> 16 };
        h16x8 gc[4];
#pragma unroll
        for (int c = 0; c < 4; c++)
            gc[c] = *(const h16x8*)((const char*)stage + (((code[c] & 0x7FFu) ^ (unsigned)cch) << 4));

        if (__builtin_expect((a01 | a23) & 0x80008000u, 0)) {
#pragma unroll
            for (int c = 0; c < 4; c++)
                if (code[c] & 0x8000u)
                    gc[c] = *(const h16x8*)(xb + (size_t)(code[c] & 0x7fffu) * 64 + c0);
        }

        _Float16 h00 = u2h((unsigned short)(w01 & 0xffffu));
        _Float16 h01 = u2h((unsigned short)(w01 >> 16));
        _Float16 h10 = u2h((unsigned short)(w23 & 0xffffu));
        _Float16 h11 = u2h((unsigned short)(w23 >> 16));
        h16x8 bF = gc[0] * h00;
        bF = gc[1] * h01 + bF;
        bF = gc[2] * h10 + bF;
        bF = gc[3] * h11 + bF;

        h16x8 aF[4];
#pragma unroll
        for (int m = 0; m < 4; m++)
            aF[m] = wfv[((k * 4 + m) * 2 + kh) * 64 + lane];
#pragma unroll
        for (int m = 0; m < 4; m++)
            acc[m] = __builtin_amdgcn_mfma_f32_16x16x32_f16(aF[m], bF, acc[m], 0, 0, 0);
    }

    __syncthreads();
    float* red = (float*)stage;        // stage dead after main loop (16KB red fits in 20.5KB)
    if (kh == 1) {
#pragma unroll
        for (int m = 0; m < 4; m++)
#pragma unroll
            for (int j = 0; j < 4; j++)
                red[(m * 4 + j) * 256 + wv * 64 + lane] = acc[m][j];
    }
    __syncthreads();
    if (kh == 0) {
        int p = ((rowbase + wv) << 7) + colbase + tc;
        int px = (b << 14) + p;
        unsigned short* drow = outn + (size_t)px * 64;
        const unsigned short* rrow = (EPI == 1) ? residn + (size_t)px * 64 : nullptr;
#pragma unroll
        for (int m = 0; m < 4; m++) {
            int ocb = m * 16 + cg * 4;
            float rv[4] = {0.f, 0.f, 0.f, 0.f};
            if (EPI == 1) {
                ushort4 rr = *(const ushort4*)(rrow + ocb);
                rv[0] = (float)u2h(rr.x); rv[1] = (float)u2h(rr.y);
                rv[2] = (float)u2h(rr.z); rv[3] = (float)u2h(rr.w);
            }
            unsigned short pk[4];
#pragma unroll
            for (int r = 0; r < 4; r++) {
                int oc = ocb + r;
                float v = acc[m][r] + red[(m * 4 + r) * 256 + wv * 64 + lane] + bias[oc];
                if (EPI == 0) v = (v >= 0.f) ? v : 0.01f * v;
                if (EPI == 1) v += rv[r];
                pk[r] = f2h(v);
            }
            *(ushort4*)(drow + ocb) = *(ushort4*)pk;
        }
    }
}

extern "C" void kernel_launch(void* const* d_in, const int* in_sizes, int n_in,
                              void* d_out, int out_size, void* d_ws, size_t ws_size,
                              hipStream_t stream)
{
    const float* input  = (const float*)d_in[0];
    const float* offset = (const float*)d_in[1];
    const float* w_off1 = (const float*)d_in[2];
    const float* b_off1 = (const float*)d_in[3];
    const float* w1     = (const float*)d_in[4];
    const float* b1     = (const float*)d_in[5];
    const float* w_off2 = (const float*)d_in[6];
    const float* b_off2 = (const float*)d_in[7];
    const float* w2     = (const float*)d_in[8];
    const float* b2     = (const float*)d_in[9];
    const float* w_last = (const float*)d_in[10];
    const float* b_last = (const float*)d_in[11];
    float* out = (float*)d_out;

    unsigned short* xn   = (unsigned short*)d_ws;          // 4,194,304 ush
    unsigned short* offn = xn + 4194304;                   // 2,097,152 ush
    unsigned short* x1n  = offn + 2097152;                 // 4,194,304 ush
    unsigned short* x2n  = x1n + 4194304;                  // 4,194,304 ush
    unsigned short* wfo  = x2n + 4194304;                  // 36,864 ush (two 27-oc sets)
    unsigned short* wf1  = wfo + 36864;                    // 36,864 ush
    unsigned short* wf2  = wf1 + 36864;                    // 36,864 ush
    unsigned short* wfl  = wf2 + 36864;                    // 36,864 ush
    float* bias54 = (float*)(wfl + 36864);                 // 64 f

    prep<<<dim3(1089), 256, 0, stream>>>(input, offset, w_off1, w_off2, b_off1, b_off2,
                                         w1, w2, w_last, xn, offn, wfo, wf1, wf2, wfl, bias54);

    // DCN 1 (fused offset-conv set 0, 4x16 tiles, 8x20 window): sample xn, leaky -> x1n
    dcn_fused<0><<<dim3(1024), 512, 0, stream>>>(xn, offn, wfo, bias54,
                                                 wf1, b1, nullptr, x1n);
    // DCN 2 (fused offset-conv set 1): sample x1n, + xn residual (fp16 NHWC) -> x2n
    dcn_fused<1><<<dim3(1024), 512, 0, stream>>>(x1n, offn, wfo + 18432, bias54 + 27,
                                                 wf2, b2, xn, x2n);
    // final conv (4x16 tiles)
    conv_tile64<<<dim3(1024), 512, 0, stream>>>(x2n, wfl, b_last, out);
}